// Round 9
// baseline (699.056 us; speedup 1.0000x reference)
//
#include <hip/hip_runtime.h>
#include <math.h>

#define NN 20000
#define NE 320000

typedef const float* fp;
typedef short short8 __attribute__((ext_vector_type(8)));
typedef short short4v __attribute__((ext_vector_type(4)));
typedef float f32x4 __attribute__((ext_vector_type(4)));

__device__ __forceinline__ short F2B(float f) {           // exact RNE (prep only)
    unsigned u = __float_as_uint(f);
    return (short)((u + 0x7fffu + ((u >> 16) & 1u)) >> 16);
}
__device__ __forceinline__ short F2Bf(float f) {          // fast round (hot path)
    return (short)((__float_as_uint(f) + 0x8000u) >> 16);
}
__device__ __forceinline__ float B2F(short s) {
    return __uint_as_float(((unsigned)(unsigned short)s) << 16);
}
__device__ __forceinline__ float siluf(float v) { return v / (1.f + __expf(-v)); }
__device__ __forceinline__ f32x4 ld4(const float* p) {    // 16B load, 4B-aligned ok
    f32x4 v;
    __builtin_memcpy(&v, p, 16);
    return v;
}

// 16x16x16 bf16 MFMA: A/B fragment layout [m=lane&15][k=quad*4+i] matches the
// C/D layout (col=lane&15,row=quad*4+reg) -> chained MFMAs need no shuffles.
#if defined(__has_builtin)
#if __has_builtin(__builtin_amdgcn_mfma_f32_16x16x16bf16_1k)
#define MFMA16_BUILTIN 1
__device__ __forceinline__ f32x4 mfma16(short4v a, short4v b, f32x4 c) {
    return __builtin_amdgcn_mfma_f32_16x16x16bf16_1k(a, b, c, 0, 0, 0);
}
#elif __has_builtin(__builtin_amdgcn_mfma_f32_16x16x16_bf16)
#define MFMA16_BUILTIN 1
__device__ __forceinline__ f32x4 mfma16(short4v a, short4v b, f32x4 c) {
    return __builtin_amdgcn_mfma_f32_16x16x16_bf16(a, b, c, 0, 0, 0);
}
#endif
#endif
#ifndef MFMA16_BUILTIN
__device__ __forceinline__ f32x4 mfma16(short4v a, short4v b, f32x4 c) {
    f32x4 d;
    asm volatile("s_nop 1\n\tv_mfma_f32_16x16x16_bf16 %0, %1, %2, %3\n\ts_nop 7\n\ts_nop 7"
                 : "=v"(d) : "v"(a), "v"(b), "v"(c));
    return d;
}
#endif

// ---------------- weight fp32->bf16 (layout in shorts): ---------------------
// 0: e1hh[128][256] | 32768: Wc[128][256] (k_fold) | 65536: e2W | 81920: c1W
// 98304: c2W[16][128] | 100352: n1W[128][256] | 133120: n2W  end 149504
__global__ void k_prep_w(fp e1W, fp e2W, fp c1W, fp c2W, fp n1W, fp n2W,
                         short* __restrict__ wb) {
    int i = blockIdx.x * 256 + threadIdx.x;
    if (i >= 149504) return;
    if (i >= 32768 && i < 65536) return;
    float v;
    if (i < 32768)       { int o = i >> 8, k = i & 255; v = e1W[o * 384 + k]; }
    else if (i < 81920)  v = e2W[i - 65536];
    else if (i < 98304)  v = c1W[i - 81920];
    else if (i < 100352) { int q = i - 98304; v = (q < 1792) ? c2W[q] : 0.f; }
    else if (i < 133120) v = n1W[i - 100352];
    else                 v = n2W[i - 133120];
    wb[i] = F2B(v);
}

__global__ void k_fold(fp e1W, fp rW, fp rB, short* __restrict__ wb,
                       float* __restrict__ bc) {
    int o = blockIdx.x, k = threadIdx.x;
    float acc = 0.f;
    for (int m = 0; m < 128; m++) acc += e1W[o * 384 + 256 + m] * rW[m * 256 + k];
    wb[32768 + o * 256 + k] = F2B(acc);
    if (k == 0) {
        float b = 0.f;
        for (int m = 0; m < 128; m++) b += e1W[o * 384 + 256 + m] * rB[m];
        bc[o] = b;
    }
}

__global__ void k_prep_h(fp h, short* __restrict__ hb) {
    int i = blockIdx.x * 256 + threadIdx.x;
    if (i < NN * 128) hb[i] = F2B(h[i]);
}

// attrTw[n][a(16)][c(16)] = attr[n][c][a] * cw[n][c], c>=14 zero.
__global__ void k_prep_attrT(fp attr, fp cw, short* __restrict__ aT) {
    int i = blockIdx.x * 256 + threadIdx.x;
    if (i >= NN * 256) return;
    int n = i >> 8, rem = i & 255, c = rem >> 4, a = rem & 15;
    float v = (c < 14) ? attr[(size_t)n * 224 + c * 16 + a] * cw[n * 14 + c] : 0.f;
    aT[(size_t)n * 256 + a * 16 + c] = F2B(v);
}

__global__ void k_node_pre(fp x, fp cw, float* __restrict__ csum, float* __restrict__ pool) {
    int n = blockIdx.x * blockDim.x + threadIdx.x;
    if (n >= NN) return;
    float cnt = 0.f, px = 0.f, py = 0.f, pz = 0.f;
#pragma unroll
    for (int c = 0; c < 14; c++) {
        float w = cw[n * 14 + c];
        if (w != 0.f) {
            cnt += 1.f;
            px += x[(n * 14 + c) * 3 + 0];
            py += x[(n * 14 + c) * 3 + 1];
            pz += x[(n * 14 + c) * 3 + 2];
        }
    }
    if (cnt < 1.f) cnt = 1.f;
    csum[n] = cnt;
    pool[n * 3 + 0] = px / cnt;
    pool[n * 3 + 1] = py / cnt;
    pool[n * 3 + 2] = pz / cnt;
}

// ---------------- merged prep (split path): count+prep_w+fold+prep_h+node_pre+attrT
__global__ void k_prep_all(fp e1W, fp e2W, fp c1W, fp c2W, fp n1W, fp n2W,
                           fp rW, fp rB, fp h, fp x, fp attr, fp cw,
                           const int* __restrict__ row, const int* __restrict__ col,
                           short* __restrict__ wb, float* __restrict__ bc,
                           short* __restrict__ hb,
                           float* __restrict__ csum, float* __restrict__ pool,
                           short* __restrict__ aT,
                           int* __restrict__ cnt_r, int* __restrict__ cnt_c) {
    int b = blockIdx.x;
    const int tid = threadIdx.x;
    if (b < 1250) {                                   // CSR degree count
        int e = b * 256 + tid;
        if (e < NE) {
            atomicAdd(&cnt_c[col[e]], 1);
            atomicAdd(&cnt_r[row[e]], 1);
        }
        return;
    }
    b -= 1250;
    if (b < 584) {                                    // weights -> bf16
        int i = b * 256 + tid;
        if (i >= 149504) return;
        if (i >= 32768 && i < 65536) return;
        float v;
        if (i < 32768)       { int o = i >> 8, k = i & 255; v = e1W[o * 384 + k]; }
        else if (i < 81920)  v = e2W[i - 65536];
        else if (i < 98304)  v = c1W[i - 81920];
        else if (i < 100352) { int q = i - 98304; v = (q < 1792) ? c2W[q] : 0.f; }
        else if (i < 133120) v = n1W[i - 100352];
        else                 v = n2W[i - 133120];
        wb[i] = F2B(v);
        return;
    }
    b -= 584;
    if (b < 128) {                                    // fold radial_W into e1W
        int o = b, k = tid;
        float acc = 0.f;
        for (int m = 0; m < 128; m++) acc += e1W[o * 384 + 256 + m] * rW[m * 256 + k];
        wb[32768 + o * 256 + k] = F2B(acc);
        if (k == 0) {
            float bsum = 0.f;
            for (int m = 0; m < 128; m++) bsum += e1W[o * 384 + 256 + m] * rB[m];
            bc[o] = bsum;
        }
        return;
    }
    b -= 128;
    if (b < 10000) {                                  // h -> bf16 (exactly NN*128)
        int i = b * 256 + tid;
        hb[i] = F2B(h[i]);
        return;
    }
    b -= 10000;
    if (b < 79) {                                     // node pre (csum, pooled col)
        int n = b * 256 + tid;
        if (n >= NN) return;
        float cnt = 0.f, px = 0.f, py = 0.f, pz = 0.f;
#pragma unroll
        for (int c = 0; c < 14; c++) {
            float w = cw[n * 14 + c];
            if (w != 0.f) {
                cnt += 1.f;
                px += x[(n * 14 + c) * 3 + 0];
                py += x[(n * 14 + c) * 3 + 1];
                pz += x[(n * 14 + c) * 3 + 2];
            }
        }
        if (cnt < 1.f) cnt = 1.f;
        csum[n] = cnt;
        pool[n * 3 + 0] = px / cnt;
        pool[n * 3 + 1] = py / cnt;
        pool[n * 3 + 2] = pz / cnt;
        return;
    }
    b -= 79;
    {                                                 // attrT (exactly NN*256)
        int i = b * 256 + tid;
        int n = i >> 8, rem = i & 255, c = rem >> 4, a = rem & 15;
        float v = (c < 14) ? attr[(size_t)n * 224 + c * 16 + a] * cw[n * 14 + c] : 0.f;
        aT[(size_t)n * 256 + a * 16 + c] = F2B(v);
    }
}

// single block; cnt arrays become head arrays (reset to offsets)
__global__ void k_scan(int* __restrict__ cnt0, int* __restrict__ cnt1,
                       int* __restrict__ off0, int* __restrict__ off1) {
    __shared__ int part[256];
    const int tid = threadIdx.x;
    for (int a = 0; a < 2; a++) {
        int* cnt = a ? cnt1 : cnt0;
        int* off = a ? off1 : off0;
        int c0 = tid * 79, c1 = c0 + 79;
        if (c1 > 20000) c1 = 20000;
        int s = 0;
        for (int i = c0; i < c1; i++) s += cnt[i];
        part[tid] = s;
        __syncthreads();
        if (tid == 0) {
            int r = 0;
            for (int i = 0; i < 256; i++) { int t = part[i]; part[i] = r; r += t; }
        }
        __syncthreads();
        int run = part[tid];
        for (int i = c0; i < c1; i++) {
            int cv = cnt[i];
            off[i] = run;
            cnt[i] = run;     // becomes head pointer for fill
            run += cv;
        }
        if (tid == 255) off[20000] = run;   // == NE
        __syncthreads();
    }
}

__device__ __forceinline__ void gemm_lds(const short* __restrict__ A, int sA,
                                         const short* __restrict__ W, int Ws, int K,
                                         int mt, int nt0, int nts, f32x4* acc) {
    const int lane = threadIdx.x & 63;
    const short* ap = A + (mt * 16 + (lane & 15)) * sA + ((lane >> 4) * 8);
    for (int k0 = 0; k0 < K; k0 += 32) {
        short8 a = *(const short8*)(ap + k0);
#pragma unroll
        for (int t = 0; t < nts; t++) {
            short8 b = *(const short8*)(W + ((nt0 + t) * 16 + (lane & 15)) * Ws + k0 + ((lane >> 4) * 8));
            acc[t] = __builtin_amdgcn_mfma_f32_16x16x32_bf16(a, b, acc[t], 0, 0, 0);
        }
    }
}
__device__ __forceinline__ void gemm_grow(const short* __restrict__ arow,
                                          const short* __restrict__ W, int Ws, int K,
                                          int nt0, int nts, f32x4* acc) {
    const int lane = threadIdx.x & 63;
    for (int k0 = 0; k0 < K; k0 += 32) {
        short8 a = *(const short8*)(arow + k0);
#pragma unroll
        for (int t = 0; t < nts; t++) {
            short8 b = *(const short8*)(W + ((nt0 + t) * 16 + (lane & 15)) * Ws + k0 + ((lane >> 4) * 8));
            acc[t] = __builtin_amdgcn_mfma_f32_16x16x32_bf16(a, b, acc[t], 0, 0, 0);
        }
    }
}

// ---------------- merged fill + H12 (independent after scan) -----------------
// blocks [0,1250): col-sorted fill; blocks [1250,1875): per-node h@W1|h@W2
__global__ __launch_bounds__(256, 4) void k_fill_hw(
    const int* __restrict__ row, const int* __restrict__ col,
    int* __restrict__ head_r, int* __restrict__ head_c,
    int* __restrict__ rpos,
    int* __restrict__ row_s, int* __restrict__ col_s,
    const short* __restrict__ hb, const short* __restrict__ wb,
    short* __restrict__ H12) {
    __shared__ __attribute__((aligned(16))) short A[32 * 136];
    const int tid = threadIdx.x;
    if (blockIdx.x < 1250) {
        int e = blockIdx.x * 256 + tid;
        if (e >= NE) return;
        int r = row[e], c = col[e];
        int pc = atomicAdd(&head_c[c], 1);
        row_s[pc] = r;
        col_s[pc] = c;
        int pr = atomicAdd(&head_r[r], 1);
        rpos[pc] = pr;
        return;
    }
    const int lane = tid & 63, w = tid >> 6;
    const int bb = lane & 15, quad = lane >> 4;
    const int mt = w & 1, nh = w >> 1, nb0 = (blockIdx.x - 1250) * 32;
    for (int p = tid; p < 512; p += 256) {
        int i = p >> 4, v = p & 15;
        *(short8*)(A + i * 136 + v * 8) = *(const short8*)(hb + (size_t)(nb0 + i) * 128 + v * 8);
    }
    __syncthreads();
    f32x4 acc[4];
#pragma unroll
    for (int t = 0; t < 4; t++) acc[t] = (f32x4){0.f, 0.f, 0.f, 0.f};
    gemm_lds(A, 136, wb, 256, 128, mt, nh * 4, 4, acc);
#pragma unroll
    for (int t = 0; t < 4; t++)
#pragma unroll
        for (int i = 0; i < 4; i++) {
            int m = mt * 16 + quad * 4 + i, n = (nh * 4 + t) * 16 + bb;
            H12[(size_t)(nb0 + m) * 256 + n] = F2Bf(acc[t][i]);
        }
#pragma unroll
    for (int t = 0; t < 4; t++) acc[t] = (f32x4){0.f, 0.f, 0.f, 0.f};
    gemm_lds(A, 136, wb + 128, 256, 128, mt, nh * 4, 4, acc);
#pragma unroll
    for (int t = 0; t < 4; t++)
#pragma unroll
        for (int i = 0; i < 4; i++) {
            int m = mt * 16 + quad * 4 + i, n = (nh * 4 + t) * 16 + bb;
            H12[(size_t)(nb0 + m) * 256 + 128 + n] = F2Bf(acc[t][i]);
        }
}

// ---------------- merged edge kernel: 64 edges, 512 threads, 8 waves ---------
// Barrier count unchanged but covers 2x edges. LDS U[17408] is Ar[64][264]
// during the radial phase, then V1|V2 (stride 136). c2 MFMA (waves 0-3) runs
// concurrently with the gated-ef stream to e1p (waves 4-7).
__global__ __launch_bounds__(512, 4) void k_edge(
    fp x, const int* __restrict__ row_s, const int* __restrict__ col_s,
    const int* __restrict__ rpos,
    const short* __restrict__ attrT, const short* __restrict__ H12,
    const short* __restrict__ wb, const float* __restrict__ bc,
    fp e1B, fp e2B, fp aW, fp aB, fp c1B, fp c2B,
    const float* __restrict__ csum, const float* __restrict__ poolc,
    short* __restrict__ e1p, short* __restrict__ pooledb,
    float* __restrict__ pcrec) {
    __shared__ __attribute__((aligned(16))) short U[17408];
    __shared__ float s_inv[64];
    __shared__ int s_r[64], s_c[64];
    __shared__ float s_ch[64][14];
    __shared__ float s_ps[64][15];
    __shared__ float s_red8[64][8], s_gate[64];

    const int tid = threadIdx.x, lane = tid & 63, w = tid >> 6;
    const int bb = lane & 15, quad = lane >> 4;
    const int e0 = blockIdx.x * 64;
    const short* Wc = wb + 32768;
    short* Ar = U;          // stride 264 (radial phase), 64 rows
    short* V1 = U;          // stride 136 (MLP phase)
    short* V2 = U + 8704;

    if (tid < 64) { s_r[tid] = row_s[e0 + tid]; s_c[tid] = col_s[e0 + tid]; }
    __syncthreads();

    // ---- Phase A: radial production, 8 edges per wave (LDS-free loads) ----
    const int iic = bb < 14 ? bb : 13;
    const bool q3 = (quad == 3);
    const int cb = q3 ? 30 : quad * 12;   // xc base: quad 3 clamps to floats [30..41]
#pragma unroll 2
    for (int m = 0; m < 8; m++) {
        const int ei = w * 8 + m;
        const int r = s_r[ei], c = s_c[ei];
        short4v arv = *(const short4v*)(attrT + (size_t)r * 256 + bb * 16 + quad * 4);
        short4v acv = *(const short4v*)(attrT + (size_t)c * 256 + bb * 16 + quad * 4);
        const float* xrp = x + (size_t)r * 42 + iic * 3;
        float xr0 = xrp[0], xr1 = xrp[1], xr2 = xrp[2];
        const float* xcp = x + (size_t)c * 42 + cb;
        f32x4 L0 = ld4(xcp), L1 = ld4(xcp + 4), L2 = ld4(xcp + 8);
        float cxv[4], cyv[4], czv[4];
        cxv[0] = q3 ? L1[2] : L0[0]; cyv[0] = q3 ? L1[3] : L0[1]; czv[0] = q3 ? L2[0] : L0[2];
        cxv[1] = q3 ? L2[1] : L0[3]; cyv[1] = q3 ? L2[2] : L1[0]; czv[1] = q3 ? L2[3] : L1[1];
        cxv[2] = q3 ? L2[1] : L1[2]; cyv[2] = q3 ? L2[2] : L1[3]; czv[2] = q3 ? L2[3] : L2[0];
        cxv[3] = L2[1];              cyv[3] = L2[2];              czv[3] = L2[3];
        short4v msgv;
#pragma unroll
        for (int t = 0; t < 4; t++) {
            float dx = xr0 - cxv[t], dy = xr1 - cyv[t], dz = xr2 - czv[t];
            msgv[t] = F2Bf(sqrtf(dx * dx + dy * dy + dz * dz));
        }
        f32x4 t2 = mfma16(msgv, acv, (f32x4){0.f, 0.f, 0.f, 0.f});
        short4v t2v;
#pragma unroll
        for (int g = 0; g < 4; g++) t2v[g] = F2Bf(t2[g]);
        f32x4 rad = mfma16(arv, t2v, (f32x4){0.f, 0.f, 0.f, 0.f});
        float ss = rad[0] * rad[0] + rad[1] * rad[1] + rad[2] * rad[2] + rad[3] * rad[3];
#pragma unroll
        for (int off = 32; off > 0; off >>= 1) ss += __shfl_xor(ss, off, 64);
        float inv = 1.f / (sqrtf(ss) + 1.f);
        if (lane == 0) s_inv[ei] = inv;
#pragma unroll
        for (int g = 0; g < 4; g++)
            Ar[ei * 264 + (quad * 4 + g) * 16 + bb] = F2Bf(rad[g] * inv);
    }
    __syncthreads();

    // ---- Phase B: GEMM [64x256] @ Wc^T; wave w owns N cols [w*16,+16) ------
    f32x4 racc[4];
#pragma unroll
    for (int a = 0; a < 4; a++) racc[a] = (f32x4){0.f, 0.f, 0.f, 0.f};
    for (int k0 = 0; k0 < 256; k0 += 32) {
        short8 b = *(const short8*)(Wc + (size_t)(w * 16 + bb) * 256 + k0 + quad * 8);
#pragma unroll
        for (int a = 0; a < 4; a++) {
            short8 av = *(const short8*)(Ar + (a * 16 + bb) * 264 + k0 + quad * 8);
            racc[a] = __builtin_amdgcn_mfma_f32_16x16x32_bf16(av, b, racc[a], 0, 0, 0);
        }
    }
    __syncthreads();   // all Ar reads complete before V1 overwrite

    // ---- E1 -> V1 (in LDS; no global round-trip) ----
#pragma unroll
    for (int a = 0; a < 4; a++)
#pragma unroll
        for (int i = 0; i < 4; i++) {
            int m = a * 16 + quad * 4 + i, n = w * 16 + bb;
            V1[m * 136 + n] = F2Bf(racc[a][i] + s_inv[m] * bc[n]);
        }
    __syncthreads();

    // ---- stage: e1 activation (H12 gather + E1 from LDS), in place ----
    for (int p = tid; p < 1024; p += 512) {
        int e = p >> 4, v = p & 15;
        short8 hr = *(const short8*)(H12 + (size_t)s_r[e] * 256 + v * 8);
        short8 hc = *(const short8*)(H12 + (size_t)s_c[e] * 256 + 128 + v * 8);
        short8 pp = *(const short8*)(V1 + e * 136 + v * 8);
        short8 o;
#pragma unroll
        for (int j = 0; j < 8; j++)
            o[j] = F2Bf(siluf(B2F(hr[j]) + B2F(hc[j]) + B2F(pp[j]) + e1B[v * 8 + j]));
        *(short8*)(V1 + e * 136 + v * 8) = o;
    }
    __syncthreads();

    // ---- e2 GEMM: V1 -> V2 (silu epilogue); M=64: mt=w&3, nh=w>>2 ----
    const int mt = w & 3, nh = w >> 2;
    f32x4 acc[4];
#pragma unroll
    for (int t = 0; t < 4; t++) acc[t] = (f32x4){0.f, 0.f, 0.f, 0.f};
    gemm_lds(V1, 136, wb + 65536, 128, 128, mt, nh * 4, 4, acc);
#pragma unroll
    for (int t = 0; t < 4; t++)
#pragma unroll
        for (int i = 0; i < 4; i++) {
            int m = mt * 16 + quad * 4 + i, n = (nh * 4 + t) * 16 + bb;
            V2[m * 136 + n] = F2Bf(siluf(acc[t][i] + e2B[n]));
        }
    __syncthreads();

    // ---- attention gate partials ----
    {
        int e = tid >> 3, j = tid & 7;
        float s = 0.f;
        for (int f = j * 16; f < j * 16 + 16; f++) s += B2F(V2[e * 136 + f]) * aW[f];
        s_red8[e][j] = s;
    }
    __syncthreads();
    if (tid < 64) {
        float s = 0.f;
#pragma unroll
        for (int j = 0; j < 8; j++) s += s_red8[tid][j];
        s_gate[tid] = 1.f / (1.f + __expf(-(s + aB[0])));
    }
    // ---- c1 GEMM mainloop on V2 (gate-independent; overlaps gate compute) ----
#pragma unroll
    for (int t = 0; t < 4; t++) acc[t] = (f32x4){0.f, 0.f, 0.f, 0.f};
    gemm_lds(V2, 136, wb + 81920, 128, 128, mt, nh * 4, 4, acc);
    __syncthreads();   // s_gate visible; V2 mainloop reads done

    // ---- c1 epilogue with folded gate -> V1 ----
#pragma unroll
    for (int t = 0; t < 4; t++)
#pragma unroll
        for (int i = 0; i < 4; i++) {
            int m = mt * 16 + quad * 4 + i, n = (nh * 4 + t) * 16 + bb;
            V1[m * 136 + n] = F2Bf(siluf(s_gate[m] * acc[t][i] + c1B[n]));
        }
    __syncthreads();

    // ---- c2 (waves 0-3) || gated-ef stream to e1p (waves 4-7) ----
    if (w < 4) {
        f32x4 a4 = (f32x4){0.f, 0.f, 0.f, 0.f};
        gemm_lds(V1, 136, wb + 98304, 128, 128, w, 0, 1, &a4);
#pragma unroll
        for (int i = 0; i < 4; i++) {
            int m = w * 16 + quad * 4 + i;
            if (bb < 14) s_ch[m][bb] = a4[i] + c2B[bb];
        }
    } else {
        for (int p = tid - 256; p < 1024; p += 256) {
            int e = p >> 4, v = p & 15;
            short8 a = *(const short8*)(V2 + e * 136 + v * 8);
            short8 o;
#pragma unroll
            for (int j = 0; j < 8; j++) o[j] = F2Bf(B2F(a[j]) * s_gate[e]);
            *(short8*)(e1p + (size_t)(e0 + e) * 128 + v * 8) = o;
        }
    }
    __syncthreads();

    // ---- roller pooling via prefix sums; records scattered to row slots ----
    if (tid < 64) {
        int t = (int)(csum[s_r[tid]] + 0.5f) - 1;
        if (t < 0) t = 0; if (t > 13) t = 13;
        int Wd = 14 - t;
        float run = 0.f;
        s_ps[tid][0] = 0.f;
        for (int j = 0; j < 14; j++) { run += s_ch[tid][j]; s_ps[tid][j + 1] = run; }
        float invW = 1.f / (float)Wd;
        int rp = rpos[e0 + tid];
        for (int i = 0; i < 14; i++) {
            int jend = i + Wd; if (jend > 14) jend = 14;
            pooledb[(size_t)rp * 14 + i] = F2Bf((s_ps[tid][jend] - s_ps[tid][i]) * invW);
        }
        int c = s_c[tid];
        float4 pc = make_float4(poolc[c * 3 + 0], poolc[c * 3 + 1], poolc[c * 3 + 2], 0.f);
        *(float4*)(pcrec + (size_t)rp * 4) = pc;
    }
}

// ---------------- fused fallback (round-0 scalar atomics) --------------------
__global__ __launch_bounds__(256, 3) void k_edge_fused(
    fp x, const int* __restrict__ row, const int* __restrict__ col,
    fp attr, fp cw, const short* __restrict__ hb, const short* __restrict__ wb,
    fp e1B, fp e2B, fp aW, fp aB, fp c1B, fp c2B,
    const float* __restrict__ bc, const float* __restrict__ csum,
    const float* __restrict__ poolc,
    float* __restrict__ xacc, float* __restrict__ agg,
    float* __restrict__ cntr, float* __restrict__ cntc) {
    __shared__ __attribute__((aligned(16))) short R1[13056];
    __shared__ float s_xr2[32 * 42];
    __shared__ float T[4][352];
    __shared__ int   s_r[32], s_c[32];
    __shared__ float s_inv[32];
    __shared__ float s_ch[32][14], s_pool[32][14];
    __shared__ float s_red8[32][8];
    __shared__ float s_gate[32];

    const int tid = threadIdx.x, lane = tid & 63, w = tid >> 6;
    const int bb = lane & 15, quad = lane >> 4;

    if (tid < 32) { s_r[tid] = row[blockIdx.x * 32 + tid]; s_c[tid] = col[blockIdx.x * 32 + tid]; }
    __syncthreads();

    float* slot = T[w];
    float* t2w = slot + 72;
    for (int i8 = 0; i8 < 8; i8++) {
        const int e = w * 8 + i8;
        const int r = s_r[e], cl = s_c[e];
        if (lane < 42) {
            s_xr2[e * 42 + lane] = x[(size_t)r * 42 + lane];
            slot[lane] = x[(size_t)cl * 42 + lane];
        }
        if (lane < 14)      slot[42 + lane] = cw[r * 14 + lane];
        else if (lane < 28) slot[56 + (lane - 14)] = cw[cl * 14 + (lane - 14)];
        __builtin_amdgcn_wave_barrier();

        const int iic = bb < 14 ? bb : 13;
        float xr0 = s_xr2[e * 42 + iic * 3], xr1 = s_xr2[e * 42 + iic * 3 + 1],
              xr2v = s_xr2[e * 42 + iic * 3 + 2];
        float cwri = slot[42 + iic];
        short8 msgv, acv;
#pragma unroll
        for (int t = 0; t < 8; t++) {
            int jj = quad * 8 + t, jc = jj < 14 ? jj : 13;
            float dx = xr0 - slot[jc * 3], dy = xr1 - slot[jc * 3 + 1], dz = xr2v - slot[jc * 3 + 2];
            float m = sqrtf(dx * dx + dy * dy + dz * dz) * cwri * slot[56 + jc];
            msgv[t] = (bb < 14 && jj < 14) ? F2B(m) : (short)0;
            acv[t] = F2B(attr[(size_t)cl * 224 + jc * 16 + bb]);
        }
        f32x4 t2 = (f32x4){0.f, 0.f, 0.f, 0.f};
        t2 = __builtin_amdgcn_mfma_f32_16x16x32_bf16(msgv, acv, t2, 0, 0, 0);
#pragma unroll
        for (int g = 0; g < 4; g++) t2w[(quad * 4 + g) * 17 + bb] = t2[g];
        __builtin_amdgcn_wave_barrier();

        short8 arv, t2v;
#pragma unroll
        for (int t = 0; t < 8; t++) {
            int kk = quad * 8 + t, kc = kk < 16 ? kk : 15;
            t2v[t] = F2B(t2w[kc * 17 + bb]);
            arv[t] = (kk < 14) ? F2B(attr[(size_t)r * 224 + kk * 16 + bb]) : (short)0;
        }
        f32x4 rad = (f32x4){0.f, 0.f, 0.f, 0.f};
        rad = __builtin_amdgcn_mfma_f32_16x16x32_bf16(arv, t2v, rad, 0, 0, 0);

        float ss = rad[0] * rad[0] + rad[1] * rad[1] + rad[2] * rad[2] + rad[3] * rad[3];
#pragma unroll
        for (int off = 32; off > 0; off >>= 1) ss += __shfl_xor(ss, off, 64);
        float inv = 1.f / (sqrtf(ss) + 1.f);
        if (lane == 0) s_inv[e] = inv;
#pragma unroll
        for (int g = 0; g < 4; g++)
            R1[e * 264 + (quad * 4 + g) * 16 + bb] = F2B(rad[g] * inv);
        __builtin_amdgcn_wave_barrier();
    }
    __syncthreads();

    const int mt = w & 1, nh = w >> 1;
    const int m_ = mt * 16 + bb;
    f32x4 acc[4];
#pragma unroll
    for (int t = 0; t < 4; t++) acc[t] = (f32x4){0.f, 0.f, 0.f, 0.f};
    {
        const short* ar_ = hb + (size_t)s_r[m_] * 128 + quad * 8;
        const short* ac_ = hb + (size_t)s_c[m_] * 128 + quad * 8;
        gemm_grow(ar_, wb, 256, 128, nh * 4, 4, acc);
        gemm_grow(ac_, wb + 128, 256, 128, nh * 4, 4, acc);
        gemm_lds(R1, 264, wb + 32768, 256, 256, mt, nh * 4, 4, acc);
    }
    __syncthreads();
    short* V1 = R1;
    short* V2 = R1 + 4352;
    short* C1O = R1 + 8704;
#pragma unroll
    for (int t = 0; t < 4; t++)
#pragma unroll
        for (int i = 0; i < 4; i++) {
            int m = mt * 16 + quad * 4 + i, n = (nh * 4 + t) * 16 + bb;
            V1[m * 136 + n] = F2B(siluf(acc[t][i] + e1B[n] + bc[n] * s_inv[m]));
        }
    __syncthreads();

#pragma unroll
    for (int t = 0; t < 4; t++) acc[t] = (f32x4){0.f, 0.f, 0.f, 0.f};
    gemm_lds(V1, 136, wb + 65536, 128, 128, mt, nh * 4, 4, acc);
    __syncthreads();
#pragma unroll
    for (int t = 0; t < 4; t++)
#pragma unroll
        for (int i = 0; i < 4; i++) {
            int m = mt * 16 + quad * 4 + i, n = (nh * 4 + t) * 16 + bb;
            V2[m * 136 + n] = F2B(siluf(acc[t][i] + e2B[n]));
        }
    __syncthreads();

    {
        int e = tid >> 3, j = tid & 7;
        float s = 0.f;
        for (int f = j * 16; f < j * 16 + 16; f++) s += B2F(V2[e * 136 + f]) * aW[f];
        s_red8[e][j] = s;
    }
    __syncthreads();
    if (tid < 32) {
        float s = 0.f;
#pragma unroll
        for (int j = 0; j < 8; j++) s += s_red8[tid][j];
        s_gate[tid] = 1.f / (1.f + __expf(-(s + aB[0])));
    }
    __syncthreads();
    for (int p = tid; p < 32 * 128; p += 256) {
        int e = p >> 7, f = p & 127;
        V1[e * 136 + f] = F2B(B2F(V2[e * 136 + f]) * s_gate[e]);
    }
    __syncthreads();

#pragma unroll
    for (int t = 0; t < 4; t++) acc[t] = (f32x4){0.f, 0.f, 0.f, 0.f};
    gemm_lds(V1, 136, wb + 81920, 128, 128, mt, nh * 4, 4, acc);
    __syncthreads();
#pragma unroll
    for (int t = 0; t < 4; t++)
#pragma unroll
        for (int i = 0; i < 4; i++) {
            int m = mt * 16 + quad * 4 + i, n = (nh * 4 + t) * 16 + bb;
            C1O[m * 136 + n] = F2B(siluf(acc[t][i] + c1B[n]));
        }
    __syncthreads();

    if (nh == 0) {
        f32x4 a4 = (f32x4){0.f, 0.f, 0.f, 0.f};
        gemm_lds(C1O, 136, wb + 98304, 128, 128, mt, 0, 1, &a4);
#pragma unroll
        for (int i = 0; i < 4; i++) {
            int m = mt * 16 + quad * 4 + i;
            if (bb < 14) s_ch[m][bb] = a4[i] + c2B[bb];
        }
    }
    __syncthreads();

    if (tid < 32) {
        int t = (int)(csum[s_r[tid]] + 0.5f) - 1;
        if (t < 0) t = 0; if (t > 13) t = 13;
        int Wd = 14 - t;
        for (int i = 0; i < 14; i++) {
            int jend = i + Wd - 1; if (jend > 13) jend = 13;
            float a = 0.f;
            for (int j = i; j <= jend; j++) a += s_ch[tid][j];
            s_pool[tid][i] = a / (float)Wd;
        }
    }
    __syncthreads();

    for (int p = tid; p < 32 * 42; p += 256) {
        int e = p / 42, q = p - e * 42, i = q / 3, d = q - i * 3;
        float diff = s_xr2[e * 42 + q] - poolc[s_c[e] * 3 + d];
        atomicAdd(&xacc[(size_t)s_r[e] * 42 + q], diff * s_pool[e][i]);
    }
    for (int p = tid; p < 32 * 128; p += 256) {
        int e = p >> 7, f = p & 127;
        atomicAdd(&agg[(size_t)s_c[e] * 128 + f], B2F(V1[e * 136 + f]));
    }
    if (tid < 32) {
        atomicAdd(&cntr[s_r[tid]], 1.f);
        atomicAdd(&cntc[s_c[tid]], 1.f);
    }
}

// ---------------- batched node post, CSR-gather (fully sequential) -----------
__global__ __launch_bounds__(256, 4) void k_node_post_csr(
    fp h, fp x, const short* __restrict__ wb,
    fp n1B, fp n2B, fp lng, fp lnb,
    const short* __restrict__ efb, const short* __restrict__ pooledb,
    const int* __restrict__ off_c, const int* __restrict__ off_r,
    const float* __restrict__ pcrec,
    float* __restrict__ outh, float* __restrict__ outx) {
    __shared__ __attribute__((aligned(16))) short nA[32 * 264];   // nY (f32 [32][128]) aliases this after GEMM1
    __shared__ __attribute__((aligned(16))) short nMid[32 * 136];
    __shared__ float nred8[32][8];
    __shared__ float nmu[32], nrs[32];
    float* nY = (float*)nA;

    const int tid = threadIdx.x;
    const int wave = tid >> 6, mt = wave & 1, nh = wave >> 1;
    const int lane = tid & 63, bb = lane & 15, quad = lane >> 4;
    const int nb0 = blockIdx.x * 32;
    const short* n1Wb = wb + 100352;
    const short* n2Wb = wb + 133120;

    for (int p = tid; p < 32 * 128; p += 256) {
        int i = p >> 7, f = p & 127;
        nA[i * 264 + f] = F2Bf(h[(size_t)(nb0 + i) * 128 + f]);
    }
    // agg gather: col-sorted efb rows are a CONTIGUOUS range per node
    {
        const int ni = tid >> 3, seg = tid & 7;
        const int n = nb0 + ni;
        const int beg = off_c[n], end = off_c[n + 1];
        float av[16];
#pragma unroll
        for (int j = 0; j < 16; j++) av[j] = 0.f;
        for (int k = beg; k < end; k++) {
            short8 u0 = *(const short8*)(efb + (size_t)k * 128 + seg * 16);
            short8 u1 = *(const short8*)(efb + (size_t)k * 128 + seg * 16 + 8);
#pragma unroll
            for (int j = 0; j < 8; j++) { av[j] += B2F(u0[j]); av[8 + j] += B2F(u1[j]); }
        }
        float inv = 1.f / fmaxf((float)(end - beg), 1.f);
#pragma unroll
        for (int j = 0; j < 16; j++)
            nA[ni * 264 + 128 + seg * 16 + j] = F2Bf(av[j] * inv);
    }
    __syncthreads();

    f32x4 acc[4];
#pragma unroll
    for (int t = 0; t < 4; t++) acc[t] = (f32x4){0.f, 0.f, 0.f, 0.f};
    gemm_lds(nA, 264, n1Wb, 256, 256, mt, nh * 4, 4, acc);
#pragma unroll
    for (int t = 0; t < 4; t++)
#pragma unroll
        for (int i = 0; i < 4; i++) {
            int m = mt * 16 + quad * 4 + i, n = (nh * 4 + t) * 16 + bb;
            nMid[m * 136 + n] = F2Bf(siluf(acc[t][i] + n1B[n]));
        }
    __syncthreads();   // after this, nA is dead -> nY may be written

#pragma unroll
    for (int t = 0; t < 4; t++) acc[t] = (f32x4){0.f, 0.f, 0.f, 0.f};
    gemm_lds(nMid, 136, n2Wb, 128, 128, mt, nh * 4, 4, acc);
#pragma unroll
    for (int t = 0; t < 4; t++)
#pragma unroll
        for (int i = 0; i < 4; i++) {
            int m = mt * 16 + quad * 4 + i, n = (nh * 4 + t) * 16 + bb;
            nY[m * 128 + n] = acc[t][i] + n2B[n] + h[(size_t)(nb0 + m) * 128 + n];
        }
    __syncthreads();

    {
        int i = tid >> 3, j = tid & 7;
        float s = 0.f;
        for (int f = j * 16; f < j * 16 + 16; f++) s += nY[i * 128 + f];
        nred8[i][j] = s;
    }
    __syncthreads();
    if (tid < 32) {
        float s = 0.f;
#pragma unroll
        for (int j = 0; j < 8; j++) s += nred8[tid][j];
        nmu[tid] = s * (1.f / 128.f);
    }
    __syncthreads();
    {
        int i = tid >> 3, j = tid & 7;
        float mu = nmu[i], s = 0.f;
        for (int f = j * 16; f < j * 16 + 16; f++) { float d = nY[i * 128 + f] - mu; s += d * d; }
        nred8[i][j] = s;
    }
    __syncthreads();
    if (tid < 32) {
        float s = 0.f;
#pragma unroll
        for (int j = 0; j < 8; j++) s += nred8[tid][j];
        nrs[tid] = rsqrtf(s * (1.f / 128.f) + 1e-5f);
    }
    __syncthreads();
    for (int p = tid; p < 32 * 128; p += 256) {
        int i = p >> 7, f = p & 127;
        outh[(size_t)(nb0 + i) * 128 + f] = (nY[i * 128 + f] - nmu[i]) * nrs[i] * lng[f] + lnb[f];
    }
    // x_out via row-CSR: pooledb/pcrec are ROW-sorted -> sequential reads.
    for (int p = tid; p < 32 * 3; p += 256) {
        int i = p / 3, d = p - i * 3;
        int n = nb0 + i;
        int beg = off_r[n], end = off_r[n + 1];
        float Q[14], P[14];
#pragma unroll
        for (int ic = 0; ic < 14; ic++) { Q[ic] = 0.f; P[ic] = 0.f; }
        for (int k = beg; k < end; k++) {
            const int* pp = (const int*)(pooledb + (size_t)k * 14);
            float4 pc = *(const float4*)(pcrec + (size_t)k * 4);
            float pcd = (d == 0) ? pc.x : ((d == 1) ? pc.y : pc.z);
#pragma unroll
            for (int u2 = 0; u2 < 7; u2++) {
                int u = pp[u2];
                float pw0 = B2F((short)(u & 0xffff));
                float pw1 = B2F((short)(((unsigned)u) >> 16));
                P[2 * u2] += pw0;     Q[2 * u2] += pw0 * pcd;
                P[2 * u2 + 1] += pw1; Q[2 * u2 + 1] += pw1 * pcd;
            }
        }
        float invd = 1.f / fmaxf((float)(end - beg), 1.f);
#pragma unroll
        for (int ic = 0; ic < 14; ic++) {
            float x0 = x[(size_t)n * 42 + ic * 3 + d];
            outx[(size_t)n * 42 + ic * 3 + d] = x0 + (x0 * P[ic] - Q[ic]) * invd;
        }
    }
}

// ---------------- batched node post (fallback, atomic buffers) ---------------
__global__ __launch_bounds__(256, 2) void k_node_post(
    fp h, fp x, const short* __restrict__ wb,
    fp n1B, fp n2B, fp lng, fp lnb,
    const float* __restrict__ agg, const float* __restrict__ cntc,
    const float* __restrict__ xacc, const float* __restrict__ cntr,
    float* __restrict__ outh, float* __restrict__ outx) {
    __shared__ __attribute__((aligned(16))) short nA[32 * 264];
    __shared__ __attribute__((aligned(16))) short nMid[32 * 136];
    __shared__ float nY[32][128];
    __shared__ float nred8[32][8];
    __shared__ float nmu[32], nrs[32];

    const int tid = threadIdx.x;
    const int wave = tid >> 6, mt = wave & 1, nh = wave >> 1;
    const int lane = tid & 63, bb = lane & 15, quad = lane >> 4;
    const int nb0 = blockIdx.x * 32;
    const short* n1Wb = wb + 100352;
    const short* n2Wb = wb + 133120;

    for (int p = tid; p < 32 * 128; p += 256) {
        int i = p >> 7, f = p & 127;
        int n = nb0 + i;
        nA[i * 264 + f] = F2Bf(h[(size_t)n * 128 + f]);
        float cc = cntc[n]; if (cc < 1.f) cc = 1.f;
        nA[i * 264 + 128 + f] = F2Bf(agg[(size_t)n * 128 + f] / cc);
    }
    __syncthreads();

    f32x4 acc[4];
#pragma unroll
    for (int t = 0; t < 4; t++) acc[t] = (f32x4){0.f, 0.f, 0.f, 0.f};
    gemm_lds(nA, 264, n1Wb, 256, 256, mt, nh * 4, 4, acc);
#pragma unroll
    for (int t = 0; t < 4; t++)
#pragma unroll
        for (int i = 0; i < 4; i++) {
            int m = mt * 16 + quad * 4 + i, n = (nh * 4 + t) * 16 + bb;
            nMid[m * 136 + n] = F2Bf(siluf(acc[t][i] + n1B[n]));
        }
    __syncthreads();

#pragma unroll
    for (int t = 0; t < 4; t++) acc[t] = (f32x4){0.f, 0.f, 0.f, 0.f};
    gemm_lds(nMid, 136, n2Wb, 128, 128, mt, nh * 4, 4, acc);
#pragma unroll
    for (int t = 0; t < 4; t++)
#pragma unroll
        for (int i = 0; i < 4; i++) {
            int m = mt * 16 + quad * 4 + i, n = (nh * 4 + t) * 16 + bb;
            nY[m][n] = acc[t][i] + n2B[n] + h[(size_t)(nb0 + m) * 128 + n];
        }
    __syncthreads();

    {
        int i = tid >> 3, j = tid & 7;
        float s = 0.f;
        for (int f = j * 16; f < j * 16 + 16; f++) s += nY[i][f];
        nred8[i][j] = s;
    }
    __syncthreads();
    if (tid < 32) {
        float s = 0.f;
#pragma unroll
        for (int j = 0; j < 8; j++) s += nred8[tid][j];
        nmu[tid] = s * (1.f / 128.f);
    }
    __syncthreads();
    {
        int i = tid >> 3, j = tid & 7;
        float mu = nmu[i], s = 0.f;
        for (int f = j * 16; f < j * 16 + 16; f++) { float d = nY[i][f] - mu; s += d * d; }
        nred8[i][j] = s;
    }
    __syncthreads();
    if (tid < 32) {
        float s = 0.f;
#pragma unroll
        for (int j = 0; j < 8; j++) s += nred8[tid][j];
        nrs[tid] = rsqrtf(s * (1.f / 128.f) + 1e-5f);
    }
    __syncthreads();
    for (int p = tid; p < 32 * 128; p += 256) {
        int i = p >> 7, f = p & 127;
        outh[(size_t)(nb0 + i) * 128 + f] = (nY[i][f] - nmu[i]) * nrs[i] * lng[f] + lnb[f];
    }
    for (int p = tid; p < 32 * 42; p += 256) {
        int i = p / 42, q = p - i * 42;
        int n = nb0 + i;
        float cr = cntr[n]; if (cr < 1.f) cr = 1.f;
        outx[(size_t)n * 42 + q] = x[(size_t)n * 42 + q] + xacc[(size_t)n * 42 + q] / cr;
    }
}

extern "C" void kernel_launch(void* const* d_in, const int* in_sizes, int n_in,
                              void* d_out, int out_size, void* d_ws, size_t ws_size,
                              hipStream_t stream) {
    fp h   = (fp)d_in[0];
    fp x   = (fp)d_in[1];
    const int* row = (const int*)d_in[2];
    const int* col = (const int*)d_in[3];
    fp attr= (fp)d_in[4];
    fp cw  = (fp)d_in[5];
    fp rW  = (fp)d_in[6];  fp rB  = (fp)d_in[7];
    fp e1W = (fp)d_in[8];  fp e1B = (fp)d_in[9];
    fp e2W = (fp)d_in[10]; fp e2B = (fp)d_in[11];
    fp aW  = (fp)d_in[12]; fp aB  = (fp)d_in[13];
    fp c1W = (fp)d_in[14]; fp c1B = (fp)d_in[15];
    fp c2W = (fp)d_in[16]; fp c2B = (fp)d_in[17];
    fp n1W = (fp)d_in[18]; fp n1B = (fp)d_in[19];
    fp n2W = (fp)d_in[20]; fp n2B = (fp)d_in[21];
    fp lng = (fp)d_in[22]; fp lnb = (fp)d_in[23];

    // fp32-offset layout (fallback): xacc 0 | agg 840000 | cntr 3400000 |
    // cntc 3420000 | csum 3440000 | pool 3460000 | bc 3520000 | hb 3520128 |
    // wb 4800128 | H12 4874880 | e1p 7434880 | attrT 27914880 | end 30474880
    // Split path overlays: CSR ints [0, 1040004) (rpos replaces eidx_r);
    // pooledb (stride-14 bf16, ROW-sorted) at [1040004, 3280004) in the dead
    // fallback region; pcrec (ROW-sorted float4) reuses hb after k_fill_hw.
    float* ws    = (float*)d_ws;
    int*   wsi   = (int*)d_ws;
    float* xacc  = ws;
    float* agg   = ws + 840000;
    float* cntr  = ws + 3400000;
    float* cntc  = ws + 3420000;
    float* csum  = ws + 3440000;
    float* pool  = ws + 3460000;
    float* bc    = ws + 3520000;
    short* hb    = (short*)(ws + 3520128);
    short* wb    = (short*)(ws + 4800128);
    short* H12   = (short*)(ws + 4874880);
    short* e1p   = (short*)(ws + 7434880);
    short* attrT = (short*)(ws + 27914880);
    short* pooledb = (short*)(ws + 1040004); // [1040004, 3280004) floats
    float* pcrec   = ws + 3520128;           // reused after k_fill_hw retires hb

    int* off_c  = wsi + 0;         // 20001
    int* off_r  = wsi + 20002;     // 20001
    int* head_c = wsi + 40004;     // 20000 (counts, then heads)
    int* head_r = wsi + 60004;     // 20000
    int* rpos   = wsi + 80004;     // 320000 (col-sorted pos -> row-CSR slot)
    int* row_s  = wsi + 400004;    // 320000
    int* col_s  = wsi + 720004;    // 320000  end 1040004

    const size_t need = 30474880ull * 4ull;

    if (ws_size >= need) {
        hipMemsetAsync(head_c, 0, 40000 * sizeof(int), stream);
        // merged preps: count(1250) + prep_w(584) + fold(128) + prep_h(10000)
        //             + node_pre(79) + attrT(20000) = 32041 blocks
        k_prep_all<<<32041, 256, 0, stream>>>(e1W, e2W, c1W, c2W, n1W, n2W,
                                              rW, rB, h, x, attr, cw, row, col,
                                              wb, bc, hb, csum, pool, attrT,
                                              head_r, head_c);
        k_scan<<<1, 256, 0, stream>>>(head_c, head_r, off_c, off_r);
        k_fill_hw<<<1250 + 625, 256, 0, stream>>>(row, col, head_r, head_c,
                                                  rpos, row_s, col_s,
                                                  hb, wb, H12);
        k_edge<<<NE / 64, 512, 0, stream>>>(x, row_s, col_s, rpos, attrT, H12, wb, bc,
                                            e1B, e2B, aW, aB, c1B, c2B,
                                            csum, pool, e1p, pooledb, pcrec);
        float* outh = (float*)d_out;
        float* outx = outh + NN * 128;
        k_node_post_csr<<<NN / 32, 256, 0, stream>>>(h, x, wb, n1B, n2B, lng, lnb,
                                                     e1p, pooledb,
                                                     off_c, off_r,
                                                     pcrec, outh, outx);
    } else {
        hipMemsetAsync(d_ws, 0, 3440000 * sizeof(float), stream);
        k_prep_w<<<(149504 + 255) / 256, 256, 0, stream>>>(e1W, e2W, c1W, c2W, n1W, n2W, wb);
        k_fold<<<128, 256, 0, stream>>>(e1W, rW, rB, wb, bc);
        k_prep_h<<<(NN * 128 + 255) / 256, 256, 0, stream>>>(h, hb);
        k_node_pre<<<(NN + 255) / 256, 256, 0, stream>>>(x, cw, csum, pool);
        k_edge_fused<<<NE / 32, 256, 0, stream>>>(x, row, col, attr, cw, hb, wb,
                                                  e1B, e2B, aW, aB, c1B, c2B,
                                                  bc, csum, pool, xacc, agg, cntr, cntc);
        float* outh = (float*)d_out;
        float* outx = outh + NN * 128;
        k_node_post<<<NN / 32, 256, 0, stream>>>(h, x, wb, n1B, n2B, lng, lnb,
                                                 agg, cntc, xacc, cntr, outh, outx);
    }
}

// Round 10
// 657.661 us; speedup vs baseline: 1.0629x; 1.0629x over previous
//
#include <hip/hip_runtime.h>
#include <math.h>

#define NN 20000
#define NE 320000

typedef const float* fp;
typedef short short8 __attribute__((ext_vector_type(8)));
typedef short short4v __attribute__((ext_vector_type(4)));
typedef float f32x4 __attribute__((ext_vector_type(4)));

__device__ __forceinline__ short F2B(float f) {           // exact RNE (prep only)
    unsigned u = __float_as_uint(f);
    return (short)((u + 0x7fffu + ((u >> 16) & 1u)) >> 16);
}
__device__ __forceinline__ short F2Bf(float f) {          // fast round (hot path)
    return (short)((__float_as_uint(f) + 0x8000u) >> 16);
}
__device__ __forceinline__ float B2F(short s) {
    return __uint_as_float(((unsigned)(unsigned short)s) << 16);
}
__device__ __forceinline__ float siluf(float v) { return v / (1.f + __expf(-v)); }
__device__ __forceinline__ f32x4 ld4(const float* p) {    // 16B load, 4B-aligned ok
    f32x4 v;
    __builtin_memcpy(&v, p, 16);
    return v;
}

// 16x16x16 bf16 MFMA: A/B fragment layout [m=lane&15][k=quad*4+i] matches the
// C/D layout (col=lane&15,row=quad*4+reg) -> chained MFMAs need no shuffles.
#if defined(__has_builtin)
#if __has_builtin(__builtin_amdgcn_mfma_f32_16x16x16bf16_1k)
#define MFMA16_BUILTIN 1
__device__ __forceinline__ f32x4 mfma16(short4v a, short4v b, f32x4 c) {
    return __builtin_amdgcn_mfma_f32_16x16x16bf16_1k(a, b, c, 0, 0, 0);
}
#elif __has_builtin(__builtin_amdgcn_mfma_f32_16x16x16_bf16)
#define MFMA16_BUILTIN 1
__device__ __forceinline__ f32x4 mfma16(short4v a, short4v b, f32x4 c) {
    return __builtin_amdgcn_mfma_f32_16x16x16_bf16(a, b, c, 0, 0, 0);
}
#endif
#endif
#ifndef MFMA16_BUILTIN
__device__ __forceinline__ f32x4 mfma16(short4v a, short4v b, f32x4 c) {
    f32x4 d;
    asm volatile("s_nop 1\n\tv_mfma_f32_16x16x16_bf16 %0, %1, %2, %3\n\ts_nop 7\n\ts_nop 7"
                 : "=v"(d) : "v"(a), "v"(b), "v"(c));
    return d;
}
#endif

// ---------------- weight fp32->bf16 (layout in shorts): ---------------------
// 0: e1hh[128][256] | 32768: Wc[128][256] (k_fold) | 65536: e2W | 81920: c1W
// 98304: c2W[16][128] | 100352: n1W[128][256] | 133120: n2W  end 149504
__global__ void k_prep_w(fp e1W, fp e2W, fp c1W, fp c2W, fp n1W, fp n2W,
                         short* __restrict__ wb) {
    int i = blockIdx.x * 256 + threadIdx.x;
    if (i >= 149504) return;
    if (i >= 32768 && i < 65536) return;
    float v;
    if (i < 32768)       { int o = i >> 8, k = i & 255; v = e1W[o * 384 + k]; }
    else if (i < 81920)  v = e2W[i - 65536];
    else if (i < 98304)  v = c1W[i - 81920];
    else if (i < 100352) { int q = i - 98304; v = (q < 1792) ? c2W[q] : 0.f; }
    else if (i < 133120) v = n1W[i - 100352];
    else                 v = n2W[i - 133120];
    wb[i] = F2B(v);
}

__global__ void k_fold(fp e1W, fp rW, fp rB, short* __restrict__ wb,
                       float* __restrict__ bc) {
    int o = blockIdx.x, k = threadIdx.x;
    float acc = 0.f;
    for (int m = 0; m < 128; m++) acc += e1W[o * 384 + 256 + m] * rW[m * 256 + k];
    wb[32768 + o * 256 + k] = F2B(acc);
    if (k == 0) {
        float b = 0.f;
        for (int m = 0; m < 128; m++) b += e1W[o * 384 + 256 + m] * rB[m];
        bc[o] = b;
    }
}

__global__ void k_prep_h(fp h, short* __restrict__ hb) {
    int i = blockIdx.x * 256 + threadIdx.x;
    if (i < NN * 128) hb[i] = F2B(h[i]);
}

// attrTw[n][a(16)][c(16)] = attr[n][c][a] * cw[n][c], c>=14 zero.
__global__ void k_prep_attrT(fp attr, fp cw, short* __restrict__ aT) {
    int i = blockIdx.x * 256 + threadIdx.x;
    if (i >= NN * 256) return;
    int n = i >> 8, rem = i & 255, c = rem >> 4, a = rem & 15;
    float v = (c < 14) ? attr[(size_t)n * 224 + c * 16 + a] * cw[n * 14 + c] : 0.f;
    aT[(size_t)n * 256 + a * 16 + c] = F2B(v);
}

__global__ void k_node_pre(fp x, fp cw, float* __restrict__ csum, float* __restrict__ pool) {
    int n = blockIdx.x * blockDim.x + threadIdx.x;
    if (n >= NN) return;
    float cnt = 0.f, px = 0.f, py = 0.f, pz = 0.f;
#pragma unroll
    for (int c = 0; c < 14; c++) {
        float w = cw[n * 14 + c];
        if (w != 0.f) {
            cnt += 1.f;
            px += x[(n * 14 + c) * 3 + 0];
            py += x[(n * 14 + c) * 3 + 1];
            pz += x[(n * 14 + c) * 3 + 2];
        }
    }
    if (cnt < 1.f) cnt = 1.f;
    csum[n] = cnt;
    pool[n * 3 + 0] = px / cnt;
    pool[n * 3 + 1] = py / cnt;
    pool[n * 3 + 2] = pz / cnt;
}

// ---------------- merged prep (split path): count+prep_w+fold+prep_h+node_pre+attrT
__global__ void k_prep_all(fp e1W, fp e2W, fp c1W, fp c2W, fp n1W, fp n2W,
                           fp rW, fp rB, fp h, fp x, fp attr, fp cw,
                           const int* __restrict__ row, const int* __restrict__ col,
                           short* __restrict__ wb, float* __restrict__ bc,
                           short* __restrict__ hb,
                           float* __restrict__ csum, float* __restrict__ pool,
                           short* __restrict__ aT,
                           int* __restrict__ cnt_r, int* __restrict__ cnt_c) {
    int b = blockIdx.x;
    const int tid = threadIdx.x;
    if (b < 1250) {                                   // CSR degree count
        int e = b * 256 + tid;
        if (e < NE) {
            atomicAdd(&cnt_c[col[e]], 1);
            atomicAdd(&cnt_r[row[e]], 1);
        }
        return;
    }
    b -= 1250;
    if (b < 584) {                                    // weights -> bf16
        int i = b * 256 + tid;
        if (i >= 149504) return;
        if (i >= 32768 && i < 65536) return;
        float v;
        if (i < 32768)       { int o = i >> 8, k = i & 255; v = e1W[o * 384 + k]; }
        else if (i < 81920)  v = e2W[i - 65536];
        else if (i < 98304)  v = c1W[i - 81920];
        else if (i < 100352) { int q = i - 98304; v = (q < 1792) ? c2W[q] : 0.f; }
        else if (i < 133120) v = n1W[i - 100352];
        else                 v = n2W[i - 133120];
        wb[i] = F2B(v);
        return;
    }
    b -= 584;
    if (b < 128) {                                    // fold radial_W into e1W
        int o = b, k = tid;
        float acc = 0.f;
        for (int m = 0; m < 128; m++) acc += e1W[o * 384 + 256 + m] * rW[m * 256 + k];
        wb[32768 + o * 256 + k] = F2B(acc);
        if (k == 0) {
            float bsum = 0.f;
            for (int m = 0; m < 128; m++) bsum += e1W[o * 384 + 256 + m] * rB[m];
            bc[o] = bsum;
        }
        return;
    }
    b -= 128;
    if (b < 10000) {                                  // h -> bf16 (exactly NN*128)
        int i = b * 256 + tid;
        hb[i] = F2B(h[i]);
        return;
    }
    b -= 10000;
    if (b < 79) {                                     // node pre (csum, pooled col)
        int n = b * 256 + tid;
        if (n >= NN) return;
        float cnt = 0.f, px = 0.f, py = 0.f, pz = 0.f;
#pragma unroll
        for (int c = 0; c < 14; c++) {
            float w = cw[n * 14 + c];
            if (w != 0.f) {
                cnt += 1.f;
                px += x[(n * 14 + c) * 3 + 0];
                py += x[(n * 14 + c) * 3 + 1];
                pz += x[(n * 14 + c) * 3 + 2];
            }
        }
        if (cnt < 1.f) cnt = 1.f;
        csum[n] = cnt;
        pool[n * 3 + 0] = px / cnt;
        pool[n * 3 + 1] = py / cnt;
        pool[n * 3 + 2] = pz / cnt;
        return;
    }
    b -= 79;
    {                                                 // attrT (exactly NN*256)
        int i = b * 256 + tid;
        int n = i >> 8, rem = i & 255, c = rem >> 4, a = rem & 15;
        float v = (c < 14) ? attr[(size_t)n * 224 + c * 16 + a] * cw[n * 14 + c] : 0.f;
        aT[(size_t)n * 256 + a * 16 + c] = F2B(v);
    }
}

// single block; cnt arrays become head arrays (reset to offsets)
__global__ void k_scan(int* __restrict__ cnt0, int* __restrict__ cnt1,
                       int* __restrict__ off0, int* __restrict__ off1) {
    __shared__ int part[256];
    const int tid = threadIdx.x;
    for (int a = 0; a < 2; a++) {
        int* cnt = a ? cnt1 : cnt0;
        int* off = a ? off1 : off0;
        int c0 = tid * 79, c1 = c0 + 79;
        if (c1 > 20000) c1 = 20000;
        int s = 0;
        for (int i = c0; i < c1; i++) s += cnt[i];
        part[tid] = s;
        __syncthreads();
        if (tid == 0) {
            int r = 0;
            for (int i = 0; i < 256; i++) { int t = part[i]; part[i] = r; r += t; }
        }
        __syncthreads();
        int run = part[tid];
        for (int i = c0; i < c1; i++) {
            int cv = cnt[i];
            off[i] = run;
            cnt[i] = run;     // becomes head pointer for fill
            run += cv;
        }
        if (tid == 255) off[20000] = run;   // == NE
        __syncthreads();
    }
}

__device__ __forceinline__ void gemm_lds(const short* __restrict__ A, int sA,
                                         const short* __restrict__ W, int Ws, int K,
                                         int mt, int nt0, int nts, f32x4* acc) {
    const int lane = threadIdx.x & 63;
    const short* ap = A + (mt * 16 + (lane & 15)) * sA + ((lane >> 4) * 8);
    for (int k0 = 0; k0 < K; k0 += 32) {
        short8 a = *(const short8*)(ap + k0);
#pragma unroll
        for (int t = 0; t < nts; t++) {
            short8 b = *(const short8*)(W + ((nt0 + t) * 16 + (lane & 15)) * Ws + k0 + ((lane >> 4) * 8));
            acc[t] = __builtin_amdgcn_mfma_f32_16x16x32_bf16(a, b, acc[t], 0, 0, 0);
        }
    }
}
__device__ __forceinline__ void gemm_grow(const short* __restrict__ arow,
                                          const short* __restrict__ W, int Ws, int K,
                                          int nt0, int nts, f32x4* acc) {
    const int lane = threadIdx.x & 63;
    for (int k0 = 0; k0 < K; k0 += 32) {
        short8 a = *(const short8*)(arow + k0);
#pragma unroll
        for (int t = 0; t < nts; t++) {
            short8 b = *(const short8*)(W + ((nt0 + t) * 16 + (lane & 15)) * Ws + k0 + ((lane >> 4) * 8));
            acc[t] = __builtin_amdgcn_mfma_f32_16x16x32_bf16(a, b, acc[t], 0, 0, 0);
        }
    }
}

// ---------------- merged fill + H12 (independent after scan) -----------------
// blocks [0,1250): col-sorted fill; blocks [1250,1875): per-node h@W1|h@W2
__global__ __launch_bounds__(256, 4) void k_fill_hw(
    const int* __restrict__ row, const int* __restrict__ col,
    int* __restrict__ head_r, int* __restrict__ head_c,
    int* __restrict__ rpos,
    int* __restrict__ row_s, int* __restrict__ col_s,
    const short* __restrict__ hb, const short* __restrict__ wb,
    short* __restrict__ H12) {
    __shared__ __attribute__((aligned(16))) short A[32 * 136];
    const int tid = threadIdx.x;
    if (blockIdx.x < 1250) {
        int e = blockIdx.x * 256 + tid;
        if (e >= NE) return;
        int r = row[e], c = col[e];
        int pc = atomicAdd(&head_c[c], 1);
        row_s[pc] = r;
        col_s[pc] = c;
        int pr = atomicAdd(&head_r[r], 1);
        rpos[pc] = pr;
        return;
    }
    const int lane = tid & 63, w = tid >> 6;
    const int bb = lane & 15, quad = lane >> 4;
    const int mt = w & 1, nh = w >> 1, nb0 = (blockIdx.x - 1250) * 32;
    for (int p = tid; p < 512; p += 256) {
        int i = p >> 4, v = p & 15;
        *(short8*)(A + i * 136 + v * 8) = *(const short8*)(hb + (size_t)(nb0 + i) * 128 + v * 8);
    }
    __syncthreads();
    f32x4 acc[4];
#pragma unroll
    for (int t = 0; t < 4; t++) acc[t] = (f32x4){0.f, 0.f, 0.f, 0.f};
    gemm_lds(A, 136, wb, 256, 128, mt, nh * 4, 4, acc);
#pragma unroll
    for (int t = 0; t < 4; t++)
#pragma unroll
        for (int i = 0; i < 4; i++) {
            int m = mt * 16 + quad * 4 + i, n = (nh * 4 + t) * 16 + bb;
            H12[(size_t)(nb0 + m) * 256 + n] = F2Bf(acc[t][i]);
        }
#pragma unroll
    for (int t = 0; t < 4; t++) acc[t] = (f32x4){0.f, 0.f, 0.f, 0.f};
    gemm_lds(A, 136, wb + 128, 256, 128, mt, nh * 4, 4, acc);
#pragma unroll
    for (int t = 0; t < 4; t++)
#pragma unroll
        for (int i = 0; i < 4; i++) {
            int m = mt * 16 + quad * 4 + i, n = (nh * 4 + t) * 16 + bb;
            H12[(size_t)(nb0 + m) * 256 + 128 + n] = F2Bf(acc[t][i]);
        }
}

// ---------------- merged edge kernel (round-8 proven 32-edge version) --------
__global__ __launch_bounds__(256, 7) void k_edge(
    fp x, const int* __restrict__ row_s, const int* __restrict__ col_s,
    const int* __restrict__ rpos,
    const short* __restrict__ attrT, const short* __restrict__ H12,
    const short* __restrict__ wb, const float* __restrict__ bc,
    fp e1B, fp e2B, fp aW, fp aB, fp c1B, fp c2B,
    const float* __restrict__ csum, const float* __restrict__ poolc,
    short* __restrict__ e1p, short* __restrict__ pooledb,
    float* __restrict__ pcrec) {
    __shared__ __attribute__((aligned(16))) short U[8704];
    __shared__ float s_inv[32];
    __shared__ int s_r[32], s_c[32];
    __shared__ float s_ch[32][14];
    __shared__ float s_ps[32][15];
    __shared__ float s_red8[32][8], s_gate[32];

    const int tid = threadIdx.x, lane = tid & 63, w = tid >> 6;
    const int bb = lane & 15, quad = lane >> 4;
    const int mt = w & 1, nh = w >> 1;
    const int e0 = blockIdx.x * 32;
    const short* Wc = wb + 32768;
    short* Ar = U;          // stride 264 (radial phase)
    short* V1 = U;          // stride 136 (MLP phase)
    short* V2 = U + 4352;

    if (tid < 32) { s_r[tid] = row_s[e0 + tid]; s_c[tid] = col_s[e0 + tid]; }
    __syncthreads();

    // ---- Phase A: radial production, 8 edges per wave (LDS-free loads) ----
    const int iic = bb < 14 ? bb : 13;
    const bool q3 = (quad == 3);
    const int cb = q3 ? 30 : quad * 12;   // xc base: quad 3 clamps to floats [30..41]
#pragma unroll 2
    for (int m = 0; m < 8; m++) {
        const int ei = w * 8 + m;
        const int r = s_r[ei], c = s_c[ei];
        short4v arv = *(const short4v*)(attrT + (size_t)r * 256 + bb * 16 + quad * 4);
        short4v acv = *(const short4v*)(attrT + (size_t)c * 256 + bb * 16 + quad * 4);
        const float* xrp = x + (size_t)r * 42 + iic * 3;
        float xr0 = xrp[0], xr1 = xrp[1], xr2 = xrp[2];
        const float* xcp = x + (size_t)c * 42 + cb;
        f32x4 L0 = ld4(xcp), L1 = ld4(xcp + 4), L2 = ld4(xcp + 8);
        float cxv[4], cyv[4], czv[4];
        cxv[0] = q3 ? L1[2] : L0[0]; cyv[0] = q3 ? L1[3] : L0[1]; czv[0] = q3 ? L2[0] : L0[2];
        cxv[1] = q3 ? L2[1] : L0[3]; cyv[1] = q3 ? L2[2] : L1[0]; czv[1] = q3 ? L2[3] : L1[1];
        cxv[2] = q3 ? L2[1] : L1[2]; cyv[2] = q3 ? L2[2] : L1[3]; czv[2] = q3 ? L2[3] : L2[0];
        cxv[3] = L2[1];              cyv[3] = L2[2];              czv[3] = L2[3];
        short4v msgv;
#pragma unroll
        for (int t = 0; t < 4; t++) {
            float dx = xr0 - cxv[t], dy = xr1 - cyv[t], dz = xr2 - czv[t];
            msgv[t] = F2Bf(sqrtf(dx * dx + dy * dy + dz * dz));
        }
        f32x4 t2 = mfma16(msgv, acv, (f32x4){0.f, 0.f, 0.f, 0.f});
        short4v t2v;
#pragma unroll
        for (int g = 0; g < 4; g++) t2v[g] = F2Bf(t2[g]);
        f32x4 rad = mfma16(arv, t2v, (f32x4){0.f, 0.f, 0.f, 0.f});
        float ss = rad[0] * rad[0] + rad[1] * rad[1] + rad[2] * rad[2] + rad[3] * rad[3];
#pragma unroll
        for (int off = 32; off > 0; off >>= 1) ss += __shfl_xor(ss, off, 64);
        float inv = 1.f / (sqrtf(ss) + 1.f);
        if (lane == 0) s_inv[ei] = inv;
#pragma unroll
        for (int g = 0; g < 4; g++)
            Ar[ei * 264 + (quad * 4 + g) * 16 + bb] = F2Bf(rad[g] * inv);
    }
    __syncthreads();

    // ---- Phase B: cooperative GEMM [32x256] @ Wc^T; wave w owns N [w*32,+32)
    f32x4 racc[2][2];
#pragma unroll
    for (int a = 0; a < 2; a++)
#pragma unroll
        for (int b = 0; b < 2; b++) racc[a][b] = (f32x4){0.f, 0.f, 0.f, 0.f};
    for (int k0 = 0; k0 < 256; k0 += 32) {
        short8 a0 = *(const short8*)(Ar + bb * 264 + k0 + quad * 8);
        short8 a1 = *(const short8*)(Ar + (16 + bb) * 264 + k0 + quad * 8);
        short8 b0 = *(const short8*)(Wc + (size_t)(w * 32 + bb) * 256 + k0 + quad * 8);
        short8 b1 = *(const short8*)(Wc + (size_t)(w * 32 + 16 + bb) * 256 + k0 + quad * 8);
        racc[0][0] = __builtin_amdgcn_mfma_f32_16x16x32_bf16(a0, b0, racc[0][0], 0, 0, 0);
        racc[0][1] = __builtin_amdgcn_mfma_f32_16x16x32_bf16(a0, b1, racc[0][1], 0, 0, 0);
        racc[1][0] = __builtin_amdgcn_mfma_f32_16x16x32_bf16(a1, b0, racc[1][0], 0, 0, 0);
        racc[1][1] = __builtin_amdgcn_mfma_f32_16x16x32_bf16(a1, b1, racc[1][1], 0, 0, 0);
    }
    __syncthreads();   // all Ar reads complete before V1 overwrite

    // ---- E1 -> V1 (in LDS; no global round-trip) ----
#pragma unroll
    for (int a = 0; a < 2; a++)
#pragma unroll
        for (int b = 0; b < 2; b++)
#pragma unroll
            for (int i = 0; i < 4; i++) {
                int m = a * 16 + quad * 4 + i, n = w * 32 + b * 16 + bb;
                V1[m * 136 + n] = F2Bf(racc[a][b][i] + s_inv[m] * bc[n]);
            }
    __syncthreads();

    // ---- stage: e1 activation (H12 gather + E1 from LDS), in place ----
    for (int p = tid; p < 512; p += 256) {
        int e = p >> 4, v = p & 15;
        short8 hr = *(const short8*)(H12 + (size_t)s_r[e] * 256 + v * 8);
        short8 hc = *(const short8*)(H12 + (size_t)s_c[e] * 256 + 128 + v * 8);
        short8 pp = *(const short8*)(V1 + e * 136 + v * 8);
        short8 o;
#pragma unroll
        for (int j = 0; j < 8; j++)
            o[j] = F2Bf(siluf(B2F(hr[j]) + B2F(hc[j]) + B2F(pp[j]) + e1B[v * 8 + j]));
        *(short8*)(V1 + e * 136 + v * 8) = o;
    }
    __syncthreads();

    // ---- e2 GEMM: V1 -> V2 (silu epilogue) ----
    f32x4 acc[4];
#pragma unroll
    for (int t = 0; t < 4; t++) acc[t] = (f32x4){0.f, 0.f, 0.f, 0.f};
    gemm_lds(V1, 136, wb + 65536, 128, 128, mt, nh * 4, 4, acc);
#pragma unroll
    for (int t = 0; t < 4; t++)
#pragma unroll
        for (int i = 0; i < 4; i++) {
            int m = mt * 16 + quad * 4 + i, n = (nh * 4 + t) * 16 + bb;
            V2[m * 136 + n] = F2Bf(siluf(acc[t][i] + e2B[n]));
        }
    __syncthreads();

    // ---- attention gate partials ----
    {
        int e = tid >> 3, j = tid & 7;
        float s = 0.f;
        for (int f = j * 16; f < j * 16 + 16; f++) s += B2F(V2[e * 136 + f]) * aW[f];
        s_red8[e][j] = s;
    }
    __syncthreads();
    if (tid < 32) {
        float s = 0.f;
#pragma unroll
        for (int j = 0; j < 8; j++) s += s_red8[tid][j];
        s_gate[tid] = 1.f / (1.f + __expf(-(s + aB[0])));
    }
    // ---- c1 GEMM mainloop on V2 (gate-independent; overlaps gate compute) ----
#pragma unroll
    for (int t = 0; t < 4; t++) acc[t] = (f32x4){0.f, 0.f, 0.f, 0.f};
    gemm_lds(V2, 136, wb + 81920, 128, 128, mt, nh * 4, 4, acc);
    __syncthreads();   // s_gate visible; V2 mainloop reads done

    // ---- c1 epilogue with folded gate -> V1; gated-ef stream -> e1p ----
#pragma unroll
    for (int t = 0; t < 4; t++)
#pragma unroll
        for (int i = 0; i < 4; i++) {
            int m = mt * 16 + quad * 4 + i, n = (nh * 4 + t) * 16 + bb;
            V1[m * 136 + n] = F2Bf(siluf(s_gate[m] * acc[t][i] + c1B[n]));
        }
    for (int p = tid; p < 512; p += 256) {
        int e = p >> 4, v = p & 15;
        short8 a = *(const short8*)(V2 + e * 136 + v * 8);
        short8 o;
#pragma unroll
        for (int j = 0; j < 8; j++) o[j] = F2Bf(B2F(a[j]) * s_gate[e]);
        *(short8*)(e1p + (size_t)(e0 + e) * 128 + v * 8) = o;
    }
    __syncthreads();

    // ---- c2 GEMM reads V1 (c1 output) ----
    if (nh == 0) {
        f32x4 a4 = (f32x4){0.f, 0.f, 0.f, 0.f};
        gemm_lds(V1, 136, wb + 98304, 128, 128, mt, 0, 1, &a4);
#pragma unroll
        for (int i = 0; i < 4; i++) {
            int m = mt * 16 + quad * 4 + i;
            if (bb < 14) s_ch[m][bb] = a4[i] + c2B[bb];
        }
    }
    __syncthreads();

    // ---- roller pooling via prefix sums; records scattered to row slots ----
    if (tid < 32) {
        int t = (int)(csum[s_r[tid]] + 0.5f) - 1;
        if (t < 0) t = 0; if (t > 13) t = 13;
        int Wd = 14 - t;
        float run = 0.f;
        s_ps[tid][0] = 0.f;
        for (int j = 0; j < 14; j++) { run += s_ch[tid][j]; s_ps[tid][j + 1] = run; }
        float invW = 1.f / (float)Wd;
        int rp = rpos[e0 + tid];
        for (int i = 0; i < 14; i++) {
            int jend = i + Wd; if (jend > 14) jend = 14;
            pooledb[(size_t)rp * 14 + i] = F2Bf((s_ps[tid][jend] - s_ps[tid][i]) * invW);
        }
        int c = s_c[tid];
        float4 pc = make_float4(poolc[c * 3 + 0], poolc[c * 3 + 1], poolc[c * 3 + 2], 0.f);
        *(float4*)(pcrec + (size_t)rp * 4) = pc;
    }
}

// ---------------- fused fallback (round-0 scalar atomics) --------------------
__global__ __launch_bounds__(256, 3) void k_edge_fused(
    fp x, const int* __restrict__ row, const int* __restrict__ col,
    fp attr, fp cw, const short* __restrict__ hb, const short* __restrict__ wb,
    fp e1B, fp e2B, fp aW, fp aB, fp c1B, fp c2B,
    const float* __restrict__ bc, const float* __restrict__ csum,
    const float* __restrict__ poolc,
    float* __restrict__ xacc, float* __restrict__ agg,
    float* __restrict__ cntr, float* __restrict__ cntc) {
    __shared__ __attribute__((aligned(16))) short R1[13056];
    __shared__ float s_xr2[32 * 42];
    __shared__ float T[4][352];
    __shared__ int   s_r[32], s_c[32];
    __shared__ float s_inv[32];
    __shared__ float s_ch[32][14], s_pool[32][14];
    __shared__ float s_red8[32][8];
    __shared__ float s_gate[32];

    const int tid = threadIdx.x, lane = tid & 63, w = tid >> 6;
    const int bb = lane & 15, quad = lane >> 4;

    if (tid < 32) { s_r[tid] = row[blockIdx.x * 32 + tid]; s_c[tid] = col[blockIdx.x * 32 + tid]; }
    __syncthreads();

    float* slot = T[w];
    float* t2w = slot + 72;
    for (int i8 = 0; i8 < 8; i8++) {
        const int e = w * 8 + i8;
        const int r = s_r[e], cl = s_c[e];
        if (lane < 42) {
            s_xr2[e * 42 + lane] = x[(size_t)r * 42 + lane];
            slot[lane] = x[(size_t)cl * 42 + lane];
        }
        if (lane < 14)      slot[42 + lane] = cw[r * 14 + lane];
        else if (lane < 28) slot[56 + (lane - 14)] = cw[cl * 14 + (lane - 14)];
        __builtin_amdgcn_wave_barrier();

        const int iic = bb < 14 ? bb : 13;
        float xr0 = s_xr2[e * 42 + iic * 3], xr1 = s_xr2[e * 42 + iic * 3 + 1],
              xr2v = s_xr2[e * 42 + iic * 3 + 2];
        float cwri = slot[42 + iic];
        short8 msgv, acv;
#pragma unroll
        for (int t = 0; t < 8; t++) {
            int jj = quad * 8 + t, jc = jj < 14 ? jj : 13;
            float dx = xr0 - slot[jc * 3], dy = xr1 - slot[jc * 3 + 1], dz = xr2v - slot[jc * 3 + 2];
            float m = sqrtf(dx * dx + dy * dy + dz * dz) * cwri * slot[56 + jc];
            msgv[t] = (bb < 14 && jj < 14) ? F2B(m) : (short)0;
            acv[t] = F2B(attr[(size_t)cl * 224 + jc * 16 + bb]);
        }
        f32x4 t2 = (f32x4){0.f, 0.f, 0.f, 0.f};
        t2 = __builtin_amdgcn_mfma_f32_16x16x32_bf16(msgv, acv, t2, 0, 0, 0);
#pragma unroll
        for (int g = 0; g < 4; g++) t2w[(quad * 4 + g) * 17 + bb] = t2[g];
        __builtin_amdgcn_wave_barrier();

        short8 arv, t2v;
#pragma unroll
        for (int t = 0; t < 8; t++) {
            int kk = quad * 8 + t, kc = kk < 16 ? kk : 15;
            t2v[t] = F2B(t2w[kc * 17 + bb]);
            arv[t] = (kk < 14) ? F2B(attr[(size_t)r * 224 + kk * 16 + bb]) : (short)0;
        }
        f32x4 rad = (f32x4){0.f, 0.f, 0.f, 0.f};
        rad = __builtin_amdgcn_mfma_f32_16x16x32_bf16(arv, t2v, rad, 0, 0, 0);

        float ss = rad[0] * rad[0] + rad[1] * rad[1] + rad[2] * rad[2] + rad[3] * rad[3];
#pragma unroll
        for (int off = 32; off > 0; off >>= 1) ss += __shfl_xor(ss, off, 64);
        float inv = 1.f / (sqrtf(ss) + 1.f);
        if (lane == 0) s_inv[e] = inv;
#pragma unroll
        for (int g = 0; g < 4; g++)
            R1[e * 264 + (quad * 4 + g) * 16 + bb] = F2B(rad[g] * inv);
        __builtin_amdgcn_wave_barrier();
    }
    __syncthreads();

    const int mt = w & 1, nh = w >> 1;
    const int m_ = mt * 16 + bb;
    f32x4 acc[4];
#pragma unroll
    for (int t = 0; t < 4; t++) acc[t] = (f32x4){0.f, 0.f, 0.f, 0.f};
    {
        const short* ar_ = hb + (size_t)s_r[m_] * 128 + quad * 8;
        const short* ac_ = hb + (size_t)s_c[m_] * 128 + quad * 8;
        gemm_grow(ar_, wb, 256, 128, nh * 4, 4, acc);
        gemm_grow(ac_, wb + 128, 256, 128, nh * 4, 4, acc);
        gemm_lds(R1, 264, wb + 32768, 256, 256, mt, nh * 4, 4, acc);
    }
    __syncthreads();
    short* V1 = R1;
    short* V2 = R1 + 4352;
    short* C1O = R1 + 8704;
#pragma unroll
    for (int t = 0; t < 4; t++)
#pragma unroll
        for (int i = 0; i < 4; i++) {
            int m = mt * 16 + quad * 4 + i, n = (nh * 4 + t) * 16 + bb;
            V1[m * 136 + n] = F2B(siluf(acc[t][i] + e1B[n] + bc[n] * s_inv[m]));
        }
    __syncthreads();

#pragma unroll
    for (int t = 0; t < 4; t++) acc[t] = (f32x4){0.f, 0.f, 0.f, 0.f};
    gemm_lds(V1, 136, wb + 65536, 128, 128, mt, nh * 4, 4, acc);
    __syncthreads();
#pragma unroll
    for (int t = 0; t < 4; t++)
#pragma unroll
        for (int i = 0; i < 4; i++) {
            int m = mt * 16 + quad * 4 + i, n = (nh * 4 + t) * 16 + bb;
            V2[m * 136 + n] = F2B(siluf(acc[t][i] + e2B[n]));
        }
    __syncthreads();

    {
        int e = tid >> 3, j = tid & 7;
        float s = 0.f;
        for (int f = j * 16; f < j * 16 + 16; f++) s += B2F(V2[e * 136 + f]) * aW[f];
        s_red8[e][j] = s;
    }
    __syncthreads();
    if (tid < 32) {
        float s = 0.f;
#pragma unroll
        for (int j = 0; j < 8; j++) s += s_red8[tid][j];
        s_gate[tid] = 1.f / (1.f + __expf(-(s + aB[0])));
    }
    __syncthreads();
    for (int p = tid; p < 32 * 128; p += 256) {
        int e = p >> 7, f = p & 127;
        V1[e * 136 + f] = F2B(B2F(V2[e * 136 + f]) * s_gate[e]);
    }
    __syncthreads();

#pragma unroll
    for (int t = 0; t < 4; t++) acc[t] = (f32x4){0.f, 0.f, 0.f, 0.f};
    gemm_lds(V1, 136, wb + 81920, 128, 128, mt, nh * 4, 4, acc);
    __syncthreads();
#pragma unroll
    for (int t = 0; t < 4; t++)
#pragma unroll
        for (int i = 0; i < 4; i++) {
            int m = mt * 16 + quad * 4 + i, n = (nh * 4 + t) * 16 + bb;
            C1O[m * 136 + n] = F2B(siluf(acc[t][i] + c1B[n]));
        }
    __syncthreads();

    if (nh == 0) {
        f32x4 a4 = (f32x4){0.f, 0.f, 0.f, 0.f};
        gemm_lds(C1O, 136, wb + 98304, 128, 128, mt, 0, 1, &a4);
#pragma unroll
        for (int i = 0; i < 4; i++) {
            int m = mt * 16 + quad * 4 + i;
            if (bb < 14) s_ch[m][bb] = a4[i] + c2B[bb];
        }
    }
    __syncthreads();

    if (tid < 32) {
        int t = (int)(csum[s_r[tid]] + 0.5f) - 1;
        if (t < 0) t = 0; if (t > 13) t = 13;
        int Wd = 14 - t;
        for (int i = 0; i < 14; i++) {
            int jend = i + Wd - 1; if (jend > 13) jend = 13;
            float a = 0.f;
            for (int j = i; j <= jend; j++) a += s_ch[tid][j];
            s_pool[tid][i] = a / (float)Wd;
        }
    }
    __syncthreads();

    for (int p = tid; p < 32 * 42; p += 256) {
        int e = p / 42, q = p - e * 42, i = q / 3, d = q - i * 3;
        float diff = s_xr2[e * 42 + q] - poolc[s_c[e] * 3 + d];
        atomicAdd(&xacc[(size_t)s_r[e] * 42 + q], diff * s_pool[e][i]);
    }
    for (int p = tid; p < 32 * 128; p += 256) {
        int e = p >> 7, f = p & 127;
        atomicAdd(&agg[(size_t)s_c[e] * 128 + f], B2F(V1[e * 136 + f]));
    }
    if (tid < 32) {
        atomicAdd(&cntr[s_r[tid]], 1.f);
        atomicAdd(&cntc[s_c[tid]], 1.f);
    }
}

// ---------------- node post, 16 nodes/block (2x grid for latency hiding) -----
__global__ __launch_bounds__(256, 6) void k_node_post_csr(
    fp h, fp x, const short* __restrict__ wb,
    fp n1B, fp n2B, fp lng, fp lnb,
    const short* __restrict__ efb, const short* __restrict__ pooledb,
    const int* __restrict__ off_c, const int* __restrict__ off_r,
    const float* __restrict__ pcrec,
    float* __restrict__ outh, float* __restrict__ outx) {
    __shared__ __attribute__((aligned(16))) short nA[16 * 264];   // nY (f32 [16][128]) aliases after GEMM1
    __shared__ __attribute__((aligned(16))) short nMid[16 * 136];
    __shared__ float nred[16][16];
    __shared__ float nmu[16], nrs[16];
    float* nY = (float*)nA;

    const int tid = threadIdx.x;
    const int w = tid >> 6;
    const int lane = tid & 63, bb = lane & 15, quad = lane >> 4;
    const int nb0 = blockIdx.x * 16;
    const short* n1Wb = wb + 100352;
    const short* n2Wb = wb + 133120;

    for (int p = tid; p < 16 * 128; p += 256) {
        int i = p >> 7, f = p & 127;
        nA[i * 264 + f] = F2Bf(h[(size_t)(nb0 + i) * 128 + f]);
    }
    // agg gather: 16 threads/node, 8 bf16 each; col-sorted rows are contiguous
    {
        const int ni = tid >> 4, seg = tid & 15;
        const int n = nb0 + ni;
        const int beg = off_c[n], end = off_c[n + 1];
        float av[8];
#pragma unroll
        for (int j = 0; j < 8; j++) av[j] = 0.f;
        for (int k = beg; k < end; k++) {
            short8 u = *(const short8*)(efb + (size_t)k * 128 + seg * 8);
#pragma unroll
            for (int j = 0; j < 8; j++) av[j] += B2F(u[j]);
        }
        float inv = 1.f / fmaxf((float)(end - beg), 1.f);
#pragma unroll
        for (int j = 0; j < 8; j++)
            nA[ni * 264 + 128 + seg * 8 + j] = F2Bf(av[j] * inv);
    }
    __syncthreads();

    // GEMM1: M=16 (mt=0), wave w owns N cols [w*32, +32)
    f32x4 acc[2];
#pragma unroll
    for (int t = 0; t < 2; t++) acc[t] = (f32x4){0.f, 0.f, 0.f, 0.f};
    gemm_lds(nA, 264, n1Wb, 256, 256, 0, w * 2, 2, acc);
#pragma unroll
    for (int t = 0; t < 2; t++)
#pragma unroll
        for (int i = 0; i < 4; i++) {
            int m = quad * 4 + i, n = (w * 2 + t) * 16 + bb;
            nMid[m * 136 + n] = F2Bf(siluf(acc[t][i] + n1B[n]));
        }
    __syncthreads();   // nA dead -> nY may be written

#pragma unroll
    for (int t = 0; t < 2; t++) acc[t] = (f32x4){0.f, 0.f, 0.f, 0.f};
    gemm_lds(nMid, 136, n2Wb, 128, 128, 0, w * 2, 2, acc);
#pragma unroll
    for (int t = 0; t < 2; t++)
#pragma unroll
        for (int i = 0; i < 4; i++) {
            int m = quad * 4 + i, n = (w * 2 + t) * 16 + bb;
            nY[m * 128 + n] = acc[t][i] + n2B[n] + h[(size_t)(nb0 + m) * 128 + n];
        }
    __syncthreads();

    {
        int i = tid >> 4, j = tid & 15;
        float s = 0.f;
        for (int f = j * 8; f < j * 8 + 8; f++) s += nY[i * 128 + f];
        nred[i][j] = s;
    }
    __syncthreads();
    if (tid < 16) {
        float s = 0.f;
#pragma unroll
        for (int j = 0; j < 16; j++) s += nred[tid][j];
        nmu[tid] = s * (1.f / 128.f);
    }
    __syncthreads();
    {
        int i = tid >> 4, j = tid & 15;
        float mu = nmu[i], s = 0.f;
        for (int f = j * 8; f < j * 8 + 8; f++) { float d = nY[i * 128 + f] - mu; s += d * d; }
        nred[i][j] = s;
    }
    __syncthreads();
    if (tid < 16) {
        float s = 0.f;
#pragma unroll
        for (int j = 0; j < 16; j++) s += nred[tid][j];
        nrs[tid] = rsqrtf(s * (1.f / 128.f) + 1e-5f);
    }
    __syncthreads();
    for (int p = tid; p < 16 * 128; p += 256) {
        int i = p >> 7, f = p & 127;
        outh[(size_t)(nb0 + i) * 128 + f] = (nY[i * 128 + f] - nmu[i]) * nrs[i] * lng[f] + lnb[f];
    }
    // x_out via row-CSR: pooledb/pcrec are ROW-sorted -> sequential reads.
    for (int p = tid; p < 16 * 3; p += 256) {
        int i = p / 3, d = p - i * 3;
        int n = nb0 + i;
        int beg = off_r[n], end = off_r[n + 1];
        float Q[14], P[14];
#pragma unroll
        for (int ic = 0; ic < 14; ic++) { Q[ic] = 0.f; P[ic] = 0.f; }
        for (int k = beg; k < end; k++) {
            const int* pp = (const int*)(pooledb + (size_t)k * 14);
            float4 pc = *(const float4*)(pcrec + (size_t)k * 4);
            float pcd = (d == 0) ? pc.x : ((d == 1) ? pc.y : pc.z);
#pragma unroll
            for (int u2 = 0; u2 < 7; u2++) {
                int u = pp[u2];
                float pw0 = B2F((short)(u & 0xffff));
                float pw1 = B2F((short)(((unsigned)u) >> 16));
                P[2 * u2] += pw0;     Q[2 * u2] += pw0 * pcd;
                P[2 * u2 + 1] += pw1; Q[2 * u2 + 1] += pw1 * pcd;
            }
        }
        float invd = 1.f / fmaxf((float)(end - beg), 1.f);
#pragma unroll
        for (int ic = 0; ic < 14; ic++) {
            float x0 = x[(size_t)n * 42 + ic * 3 + d];
            outx[(size_t)n * 42 + ic * 3 + d] = x0 + (x0 * P[ic] - Q[ic]) * invd;
        }
    }
}

// ---------------- batched node post (fallback, atomic buffers) ---------------
__global__ __launch_bounds__(256, 2) void k_node_post(
    fp h, fp x, const short* __restrict__ wb,
    fp n1B, fp n2B, fp lng, fp lnb,
    const float* __restrict__ agg, const float* __restrict__ cntc,
    const float* __restrict__ xacc, const float* __restrict__ cntr,
    float* __restrict__ outh, float* __restrict__ outx) {
    __shared__ __attribute__((aligned(16))) short nA[32 * 264];
    __shared__ __attribute__((aligned(16))) short nMid[32 * 136];
    __shared__ float nY[32][128];
    __shared__ float nred8[32][8];
    __shared__ float nmu[32], nrs[32];

    const int tid = threadIdx.x;
    const int wave = tid >> 6, mt = wave & 1, nh = wave >> 1;
    const int lane = tid & 63, bb = lane & 15, quad = lane >> 4;
    const int nb0 = blockIdx.x * 32;
    const short* n1Wb = wb + 100352;
    const short* n2Wb = wb + 133120;

    for (int p = tid; p < 32 * 128; p += 256) {
        int i = p >> 7, f = p & 127;
        int n = nb0 + i;
        nA[i * 264 + f] = F2Bf(h[(size_t)n * 128 + f]);
        float cc = cntc[n]; if (cc < 1.f) cc = 1.f;
        nA[i * 264 + 128 + f] = F2Bf(agg[(size_t)n * 128 + f] / cc);
    }
    __syncthreads();

    f32x4 acc[4];
#pragma unroll
    for (int t = 0; t < 4; t++) acc[t] = (f32x4){0.f, 0.f, 0.f, 0.f};
    gemm_lds(nA, 264, n1Wb, 256, 256, mt, nh * 4, 4, acc);
#pragma unroll
    for (int t = 0; t < 4; t++)
#pragma unroll
        for (int i = 0; i < 4; i++) {
            int m = mt * 16 + quad * 4 + i, n = (nh * 4 + t) * 16 + bb;
            nMid[m * 136 + n] = F2Bf(siluf(acc[t][i] + n1B[n]));
        }
    __syncthreads();

#pragma unroll
    for (int t = 0; t < 4; t++) acc[t] = (f32x4){0.f, 0.f, 0.f, 0.f};
    gemm_lds(nMid, 136, n2Wb, 128, 128, mt, nh * 4, 4, acc);
#pragma unroll
    for (int t = 0; t < 4; t++)
#pragma unroll
        for (int i = 0; i < 4; i++) {
            int m = mt * 16 + quad * 4 + i, n = (nh * 4 + t) * 16 + bb;
            nY[m][n] = acc[t][i] + n2B[n] + h[(size_t)(nb0 + m) * 128 + n];
        }
    __syncthreads();

    {
        int i = tid >> 3, j = tid & 7;
        float s = 0.f;
        for (int f = j * 16; f < j * 16 + 16; f++) s += nY[i][f];
        nred8[i][j] = s;
    }
    __syncthreads();
    if (tid < 32) {
        float s = 0.f;
#pragma unroll
        for (int j = 0; j < 8; j++) s += nred8[tid][j];
        nmu[tid] = s * (1.f / 128.f);
    }
    __syncthreads();
    {
        int i = tid >> 3, j = tid & 7;
        float mu = nmu[i], s = 0.f;
        for (int f = j * 16; f < j * 16 + 16; f++) { float d = nY[i][f] - mu; s += d * d; }
        nred8[i][j] = s;
    }
    __syncthreads();
    if (tid < 32) {
        float s = 0.f;
#pragma unroll
        for (int j = 0; j < 8; j++) s += nred8[tid][j];
        nrs[tid] = rsqrtf(s * (1.f / 128.f) + 1e-5f);
    }
    __syncthreads();
    for (int p = tid; p < 32 * 128; p += 256) {
        int i = p >> 7, f = p & 127;
        outh[(size_t)(nb0 + i) * 128 + f] = (nY[i][f] - nmu[i]) * nrs[i] * lng[f] + lnb[f];
    }
    for (int p = tid; p < 32 * 42; p += 256) {
        int i = p / 42, q = p - i * 42;
        int n = nb0 + i;
        float cr = cntr[n]; if (cr < 1.f) cr = 1.f;
        outx[(size_t)n * 42 + q] = x[(size_t)n * 42 + q] + xacc[(size_t)n * 42 + q] / cr;
    }
}

extern "C" void kernel_launch(void* const* d_in, const int* in_sizes, int n_in,
                              void* d_out, int out_size, void* d_ws, size_t ws_size,
                              hipStream_t stream) {
    fp h   = (fp)d_in[0];
    fp x   = (fp)d_in[1];
    const int* row = (const int*)d_in[2];
    const int* col = (const int*)d_in[3];
    fp attr= (fp)d_in[4];
    fp cw  = (fp)d_in[5];
    fp rW  = (fp)d_in[6];  fp rB  = (fp)d_in[7];
    fp e1W = (fp)d_in[8];  fp e1B = (fp)d_in[9];
    fp e2W = (fp)d_in[10]; fp e2B = (fp)d_in[11];
    fp aW  = (fp)d_in[12]; fp aB  = (fp)d_in[13];
    fp c1W = (fp)d_in[14]; fp c1B = (fp)d_in[15];
    fp c2W = (fp)d_in[16]; fp c2B = (fp)d_in[17];
    fp n1W = (fp)d_in[18]; fp n1B = (fp)d_in[19];
    fp n2W = (fp)d_in[20]; fp n2B = (fp)d_in[21];
    fp lng = (fp)d_in[22]; fp lnb = (fp)d_in[23];

    // fp32-offset layout (fallback): xacc 0 | agg 840000 | cntr 3400000 |
    // cntc 3420000 | csum 3440000 | pool 3460000 | bc 3520000 | hb 3520128 |
    // wb 4800128 | H12 4874880 | e1p 7434880 | attrT 27914880 | end 30474880
    // Split path overlays: CSR ints [0, 1040004) (rpos replaces eidx_r);
    // pooledb (stride-14 bf16, ROW-sorted) at [1040004, 3280004) in the dead
    // fallback region; pcrec (ROW-sorted float4) reuses hb after k_fill_hw.
    float* ws    = (float*)d_ws;
    int*   wsi   = (int*)d_ws;
    float* xacc  = ws;
    float* agg   = ws + 840000;
    float* cntr  = ws + 3400000;
    float* cntc  = ws + 3420000;
    float* csum  = ws + 3440000;
    float* pool  = ws + 3460000;
    float* bc    = ws + 3520000;
    short* hb    = (short*)(ws + 3520128);
    short* wb    = (short*)(ws + 4800128);
    short* H12   = (short*)(ws + 4874880);
    short* e1p   = (short*)(ws + 7434880);
    short* attrT = (short*)(ws + 27914880);
    short* pooledb = (short*)(ws + 1040004); // [1040004, 3280004) floats
    float* pcrec   = ws + 3520128;           // reused after k_fill_hw retires hb

    int* off_c  = wsi + 0;         // 20001
    int* off_r  = wsi + 20002;     // 20001
    int* head_c = wsi + 40004;     // 20000 (counts, then heads)
    int* head_r = wsi + 60004;     // 20000
    int* rpos   = wsi + 80004;     // 320000 (col-sorted pos -> row-CSR slot)
    int* row_s  = wsi + 400004;    // 320000
    int* col_s  = wsi + 720004;    // 320000  end 1040004

    const size_t need = 30474880ull * 4ull;

    if (ws_size >= need) {
        hipMemsetAsync(head_c, 0, 40000 * sizeof(int), stream);
        // merged preps: count(1250) + prep_w(584) + fold(128) + prep_h(10000)
        //             + node_pre(79) + attrT(20000) = 32041 blocks
        k_prep_all<<<32041, 256, 0, stream>>>(e1W, e2W, c1W, c2W, n1W, n2W,
                                              rW, rB, h, x, attr, cw, row, col,
                                              wb, bc, hb, csum, pool, attrT,
                                              head_r, head_c);
        k_scan<<<1, 256, 0, stream>>>(head_c, head_r, off_c, off_r);
        k_fill_hw<<<1250 + 625, 256, 0, stream>>>(row, col, head_r, head_c,
                                                  rpos, row_s, col_s,
                                                  hb, wb, H12);
        k_edge<<<NE / 32, 256, 0, stream>>>(x, row_s, col_s, rpos, attrT, H12, wb, bc,
                                            e1B, e2B, aW, aB, c1B, c2B,
                                            csum, pool, e1p, pooledb, pcrec);
        float* outh = (float*)d_out;
        float* outx = outh + NN * 128;
        k_node_post_csr<<<NN / 16, 256, 0, stream>>>(h, x, wb, n1B, n2B, lng, lnb,
                                                     e1p, pooledb,
                                                     off_c, off_r,
                                                     pcrec, outh, outx);
    } else {
        hipMemsetAsync(d_ws, 0, 3440000 * sizeof(float), stream);
        k_prep_w<<<(149504 + 255) / 256, 256, 0, stream>>>(e1W, e2W, c1W, c2W, n1W, n2W, wb);
        k_fold<<<128, 256, 0, stream>>>(e1W, rW, rB, wb, bc);
        k_prep_h<<<(NN * 128 + 255) / 256, 256, 0, stream>>>(h, hb);
        k_node_pre<<<(NN + 255) / 256, 256, 0, stream>>>(x, cw, csum, pool);
        k_edge_fused<<<NE / 32, 256, 0, stream>>>(x, row, col, attr, cw, hb, wb,
                                                  e1B, e2B, aW, aB, c1B, c2B,
                                                  bc, csum, pool, xacc, agg, cntr, cntc);
        float* outh = (float*)d_out;
        float* outx = outh + NN * 128;
        k_node_post<<<NN / 32, 256, 0, stream>>>(h, x, wb, n1B, n2B, lng, lnb,
                                                 agg, cntc, xacc, cntr, outh, outx);
    }
}